// Round 8
// baseline (230.187 us; speedup 1.0000x reference)
//
#include <hip/hip_runtime.h>
#include <hip/hip_bf16.h>

typedef __attribute__((ext_vector_type(8))) short bf16x8;
typedef __attribute__((ext_vector_type(4))) float f32x4;

__device__ __forceinline__ float sigm(float x) {
    return __builtin_amdgcn_rcpf(1.0f + __expf(-x));
}
__device__ __forceinline__ float tanh_(float x) {
    float e = __expf(2.0f * x);
    return 1.0f - 2.0f * __builtin_amdgcn_rcpf(e + 1.0f);
}
__device__ __forceinline__ ushort f2bf(float f) {   // RNE float->bf16
    uint u = __float_as_uint(f);
    u = u + 0x7FFFu + ((u >> 16) & 1u);
    return (ushort)(u >> 16);
}
__device__ __forceinline__ float bf2f(ushort s) { return __uint_as_float(((uint)s) << 16); }
__device__ __forceinline__ float sel4(f32x4 a, int k) {   // a[k], divergent k
    float lo = (k & 1) ? a[1] : a[0];
    float hi = (k & 1) ? a[3] : a[2];
    return (k & 2) ? hi : lo;
}
__device__ __forceinline__ float sel4v(float a0, float a1, float a2, float a3, int s) {
    float lo = (s & 1) ? a1 : a0;
    float hi = (s & 1) ? a3 : a2;
    return (s & 2) ? hi : lo;
}

// ============ K1: e1 LSTM(8->64) via MFMA + fused e2 xg + fused e2 recurrence ============
// 8 batches/block, 512 threads (8 waves), grid 512 -> 2 INDEPENDENT blocks/CU
// (R6 lesson: 1 block/CU with a per-step barrier exposes the full ~2900cy serial
// chain; two co-resident blocks fill each other's stalls).
// MFMA A rows 0..7 = batches, rows 8..15 provably stay zero (zero h / zero x2
// rows -> zero preacts -> h=0 fixpoint).
// e2 xg tile on wave 7 -> pe2_s in LDS; e2 recurrence (H=1) runs at kernel tail
// on 8 lanes with depth-4 register prefetch, writing dec_in[ts][4096] directly.
__global__ __launch_bounds__(512) __attribute__((amdgpu_waves_per_eu(4, 4)))
void k1_enc(
    const float* __restrict__ x,
    const float* __restrict__ e1_Wih, const float* __restrict__ e1_Whh, const float* __restrict__ e1_b,
    const float* __restrict__ e2_Wih, const float* __restrict__ e2_b,
    const float* __restrict__ e2_Whh,
    float* __restrict__ dec_in)   // [ts][4096]
{
    __shared__ float x_s[8 * 768];                          // 24 KB
    __shared__ __align__(16) ushort h_hi[2][16 * 72];       // 4.6 KB
    __shared__ __align__(16) ushort h_lo[2][16 * 72];       // 4.6 KB
    __shared__ __align__(16) ushort x2_s[2][16 * 40];       // 2.5 KB
    __shared__ __align__(16) float pe2_s[96 * 8 * 4];       // 12 KB e2 xg history

    const int t = threadIdx.x;
    const int bBase = blockIdx.x * 8;
    const int l = t & 63, wv = t >> 6;
    const int q = l & 15, sub = l >> 4;
    const int u_loc = q >> 2, g = q & 3;

    // ---- stage x (8 batches) ----
    for (int i = t; i < 8 * 768; i += 512) x_s[i] = x[(size_t)bBase * 768 + i];

    // ---- weight fragments (hi/lo bf16) ----
    auto loadW = [&](const float* rowbase, int k0, bool valid, bf16x8& hi8, bf16x8& lo8) {
        float f[8];
        if (valid) {
            float4 v0 = ((const float4*)(rowbase + k0))[0];
            float4 v1 = ((const float4*)(rowbase + k0))[1];
            f[0]=v0.x; f[1]=v0.y; f[2]=v0.z; f[3]=v0.w;
            f[4]=v1.x; f[5]=v1.y; f[6]=v1.z; f[7]=v1.w;
        } else {
            #pragma unroll
            for (int j = 0; j < 8; ++j) f[j] = 0.f;
        }
        #pragma unroll
        for (int j = 0; j < 8; ++j) {
            ushort h = f2bf(f[j]);
            hi8[j] = (short)h;
            lo8[j] = (short)f2bf(f[j] - bf2f(h));
        }
    };
    auto loadTileB = [&](int T, bf16x8& Bh0, bf16x8& Bh1, bf16x8& Bl0, bf16x8& Bl1, bf16x8& B2) {
        const bool isE2 = (T == 16);
        const bool valid = !isE2 || (u_loc == 0);
        const int wrow = isE2 ? g : (g * 64 + T * 4 + u_loc);
        const float* rowp = isE2 ? (e2_Wih + (size_t)wrow * 64) : (e1_Whh + (size_t)wrow * 64);
        loadW(rowp, sub * 8,      valid, Bh0, Bl0);
        loadW(rowp, 32 + sub * 8, valid, Bh1, Bl1);
        #pragma unroll
        for (int j = 0; j < 8; ++j) B2[j] = 0;
        if (!isE2) {
            if (sub < 3) {       // k 0-7: Wih_hi(*xhi), 8-15: Wih_hi(*xlo), 16-23: Wih_lo(*xhi)
                const float* wr = e1_Wih + (size_t)wrow * 8;
                #pragma unroll
                for (int j = 0; j < 8; ++j) {
                    float f = wr[j];
                    ushort h = f2bf(f);
                    B2[j] = (sub < 2) ? (short)h : (short)f2bf(f - bf2f(h));
                }
            } else {             // k 24,25: bias hi/lo (A2 = 1.0 there)
                float bb = e1_b[wrow];
                ushort h = f2bf(bb);
                B2[0] = (short)h; B2[1] = (short)f2bf(bb - bf2f(h));
            }
        } else if (valid && sub == 3) {
            float bb = e2_b[g];
            ushort h = f2bf(bb);
            B2[0] = (short)h; B2[1] = (short)f2bf(bb - bf2f(h));
        }
    };

    const int T0 = 2 * wv, T1 = 2 * wv + 1;
    bf16x8 B0h0, B0h1, B0l0, B0l1, B0x;
    bf16x8 B1h0, B1h1, B1l0, B1l1, B1x;
    bf16x8 B2h0, B2h1, B2l0, B2l1, B2x;
    loadTileB(T0, B0h0, B0h1, B0l0, B0l1, B0x);
    loadTileB(T1, B1h0, B1h1, B1l0, B1l1, B1x);
    if (wv == 7) loadTileB(16, B2h0, B2h1, B2l0, B2l1, B2x);

    __syncthreads();   // x_s ready

    // ---- init h = 0 (all 16 rows); x2 rows 0-7 from x[0], rows 8-15 = 0 ----
    for (int i = t; i < 16 * 72; i += 512) { h_hi[0][i] = 0; h_lo[0][i] = 0; }
    {
        int bb = t >> 5, pos = t & 31;
        ushort v0 = 0, v1 = 0;
        if (bb < 8) {
            if (pos < 24) {
                float xv = x_s[bb * 768 + (pos & 7)];
                ushort hi = f2bf(xv);
                v0 = (pos < 8) ? hi : (pos < 16) ? f2bf(xv - bf2f(hi)) : hi;
            } else if (pos == 24 || pos == 25) { v0 = 0x3F80; v1 = 0x3F80; }
        }
        x2_s[0][bb * 40 + pos] = v0;
        x2_s[1][bb * 40 + pos] = v1;
    }

    float c0r = 0.f, c1r = 0.f;
    __syncthreads();

    #pragma unroll 1
    for (int ts = 0; ts < 96; ++ts) {
        const int p = ts & 1, pn = p ^ 1;

        bf16x8 Ah0 = *(const bf16x8*)&h_hi[p][q * 72 + sub * 8];
        bf16x8 Ah1 = *(const bf16x8*)&h_hi[p][q * 72 + 32 + sub * 8];
        bf16x8 Al0 = *(const bf16x8*)&h_lo[p][q * 72 + sub * 8];
        bf16x8 Al1 = *(const bf16x8*)&h_lo[p][q * 72 + 32 + sub * 8];
        bf16x8 A2v = *(const bf16x8*)&x2_s[p][q * 40 + sub * 8];

        f32x4 a0 = {0.f,0.f,0.f,0.f}, e0 = {0.f,0.f,0.f,0.f};
        a0 = __builtin_amdgcn_mfma_f32_16x16x32_bf16(Ah0, B0h0, a0, 0, 0, 0);
        a0 = __builtin_amdgcn_mfma_f32_16x16x32_bf16(Al0, B0h0, a0, 0, 0, 0);
        a0 = __builtin_amdgcn_mfma_f32_16x16x32_bf16(Ah0, B0l0, a0, 0, 0, 0);
        e0 = __builtin_amdgcn_mfma_f32_16x16x32_bf16(Ah1, B0h1, e0, 0, 0, 0);
        e0 = __builtin_amdgcn_mfma_f32_16x16x32_bf16(Al1, B0h1, e0, 0, 0, 0);
        e0 = __builtin_amdgcn_mfma_f32_16x16x32_bf16(Ah1, B0l1, e0, 0, 0, 0);
        e0 = __builtin_amdgcn_mfma_f32_16x16x32_bf16(A2v, B0x,  e0, 0, 0, 0);

        f32x4 a1 = {0.f,0.f,0.f,0.f}, e1 = {0.f,0.f,0.f,0.f};
        a1 = __builtin_amdgcn_mfma_f32_16x16x32_bf16(Ah0, B1h0, a1, 0, 0, 0);
        a1 = __builtin_amdgcn_mfma_f32_16x16x32_bf16(Al0, B1h0, a1, 0, 0, 0);
        a1 = __builtin_amdgcn_mfma_f32_16x16x32_bf16(Ah0, B1l0, a1, 0, 0, 0);
        e1 = __builtin_amdgcn_mfma_f32_16x16x32_bf16(Ah1, B1h1, e1, 0, 0, 0);
        e1 = __builtin_amdgcn_mfma_f32_16x16x32_bf16(Al1, B1h1, e1, 0, 0, 0);
        e1 = __builtin_amdgcn_mfma_f32_16x16x32_bf16(Ah1, B1l1, e1, 0, 0, 0);
        e1 = __builtin_amdgcn_mfma_f32_16x16x32_bf16(A2v, B1x,  e1, 0, 0, 0);

        if (wv == 7) {   // e2 xg tile: h[ts-1]-based -> pe2_s[ts-1]
            f32x4 a2 = {0.f,0.f,0.f,0.f}, e2 = {0.f,0.f,0.f,0.f};
            a2 = __builtin_amdgcn_mfma_f32_16x16x32_bf16(Ah0, B2h0, a2, 0, 0, 0);
            a2 = __builtin_amdgcn_mfma_f32_16x16x32_bf16(Al0, B2h0, a2, 0, 0, 0);
            a2 = __builtin_amdgcn_mfma_f32_16x16x32_bf16(Ah0, B2l0, a2, 0, 0, 0);
            e2 = __builtin_amdgcn_mfma_f32_16x16x32_bf16(Ah1, B2h1, e2, 0, 0, 0);
            e2 = __builtin_amdgcn_mfma_f32_16x16x32_bf16(Al1, B2h1, e2, 0, 0, 0);
            e2 = __builtin_amdgcn_mfma_f32_16x16x32_bf16(Ah1, B2l1, e2, 0, 0, 0);
            e2 = __builtin_amdgcn_mfma_f32_16x16x32_bf16(A2v, B2x,  e2, 0, 0, 0);
            if (ts > 0 && u_loc == 0 && sub < 2) {
                f32x4 acc2 = a2 + e2;
                #pragma unroll
                for (int i = 0; i < 4; ++i)
                    pe2_s[((size_t)(ts - 1) * 8 + 4 * sub + i) * 4 + g] = acc2[i];
            }
        }

        // ---- in-register activations (rows 8-15 compute exact zeros) ----
        {
            f32x4 acc = a0 + e0;
            float own = sel4(acc, g);
            float r1 = __shfl_xor(sel4(acc, g ^ 1), 1);
            float r2 = __shfl_xor(sel4(acc, g ^ 2), 2);
            float r3 = __shfl_xor(sel4(acc, g ^ 3), 3);
            float pi = sel4v(own, r1, r2, r3, g);
            float pf = sel4v(own, r1, r2, r3, g ^ 1);
            float pg = sel4v(own, r1, r2, r3, g ^ 2);
            float po = sel4v(own, r1, r2, r3, g ^ 3);
            c0r = fmaf(sigm(pf), c0r, sigm(pi) * tanh_(pg));
            float hv = sigm(po) * tanh_(c0r);
            int idx = (4 * sub + g) * 72 + T0 * 4 + u_loc;
            ushort hh = f2bf(hv);
            h_hi[pn][idx] = hh;
            h_lo[pn][idx] = f2bf(hv - bf2f(hh));
        }
        {
            f32x4 acc = a1 + e1;
            float own = sel4(acc, g);
            float r1 = __shfl_xor(sel4(acc, g ^ 1), 1);
            float r2 = __shfl_xor(sel4(acc, g ^ 2), 2);
            float r3 = __shfl_xor(sel4(acc, g ^ 3), 3);
            float pi = sel4v(own, r1, r2, r3, g);
            float pf = sel4v(own, r1, r2, r3, g ^ 1);
            float pg = sel4v(own, r1, r2, r3, g ^ 2);
            float po = sel4v(own, r1, r2, r3, g ^ 3);
            c1r = fmaf(sigm(pf), c1r, sigm(pi) * tanh_(pg));
            float hv = sigm(po) * tanh_(c1r);
            int idx = (4 * sub + g) * 72 + T1 * 4 + u_loc;
            ushort hh = f2bf(hv);
            h_hi[pn][idx] = hh;
            h_lo[pn][idx] = f2bf(hv - bf2f(hh));
        }

        if (ts < 95) {   // build x2[pn] for ts+1 (rows 0-7 only)
            int bb = t >> 5, pos = t & 31;
            if (bb < 8 && pos < 24) {
                float xv = x_s[bb * 768 + (ts + 1) * 8 + (pos & 7)];
                ushort hi = f2bf(xv);
                x2_s[pn][bb * 40 + pos] = (pos < 8) ? hi : (pos < 16) ? f2bf(xv - bf2f(hi)) : hi;
            }
        }
        __syncthreads();
    }

    // ---- pe2_s[95] from final h (parity 0) ----
    if (wv == 7) {
        bf16x8 Ah0 = *(const bf16x8*)&h_hi[0][q * 72 + sub * 8];
        bf16x8 Ah1 = *(const bf16x8*)&h_hi[0][q * 72 + 32 + sub * 8];
        bf16x8 Al0 = *(const bf16x8*)&h_lo[0][q * 72 + sub * 8];
        bf16x8 Al1 = *(const bf16x8*)&h_lo[0][q * 72 + 32 + sub * 8];
        bf16x8 A2v = *(const bf16x8*)&x2_s[0][q * 40 + sub * 8];   // only k=24,25 matter
        f32x4 a2 = {0.f,0.f,0.f,0.f}, e2 = {0.f,0.f,0.f,0.f};
        a2 = __builtin_amdgcn_mfma_f32_16x16x32_bf16(Ah0, B2h0, a2, 0, 0, 0);
        a2 = __builtin_amdgcn_mfma_f32_16x16x32_bf16(Al0, B2h0, a2, 0, 0, 0);
        a2 = __builtin_amdgcn_mfma_f32_16x16x32_bf16(Ah0, B2l0, a2, 0, 0, 0);
        e2 = __builtin_amdgcn_mfma_f32_16x16x32_bf16(Ah1, B2h1, e2, 0, 0, 0);
        e2 = __builtin_amdgcn_mfma_f32_16x16x32_bf16(Al1, B2h1, e2, 0, 0, 0);
        e2 = __builtin_amdgcn_mfma_f32_16x16x32_bf16(Ah1, B2l1, e2, 0, 0, 0);
        e2 = __builtin_amdgcn_mfma_f32_16x16x32_bf16(A2v, B2x,  e2, 0, 0, 0);
        if (u_loc == 0 && sub < 2) {
            f32x4 acc2 = a2 + e2;
            #pragma unroll
            for (int i = 0; i < 4; ++i)
                pe2_s[((size_t)95 * 8 + 4 * sub + i) * 4 + g] = acc2[i];
        }
    }
    __syncthreads();

    // ---- fused e2 recurrence (H=1): 8 lanes, depth-4 register prefetch ----
    if (wv == 0 && l < 8) {
        const float w0 = e2_Whh[0], w1 = e2_Whh[1], w2 = e2_Whh[2], w3 = e2_Whh[3];
        const float4* pp4 = (const float4*)pe2_s;   // [ts][8] float4
        float4 buf[4];
        #pragma unroll
        for (int j = 0; j < 4; ++j) buf[j] = pp4[j * 8 + l];
        float h = 0.f, c = 0.f;
        #pragma unroll
        for (int ts = 0; ts < 96; ++ts) {
            float4 g4 = buf[ts & 3];
            if (ts + 4 < 96) buf[ts & 3] = pp4[(ts + 4) * 8 + l];
            float gi = fmaf(h, w0, g4.x);
            float gf = fmaf(h, w1, g4.y);
            float gg = fmaf(h, w2, g4.z);
            float go = fmaf(h, w3, g4.w);
            c = fmaf(sigm(gf), c, sigm(gi) * tanh_(gg));
            h = sigm(go) * tanh_(c);
            dec_in[(size_t)ts * 4096 + bBase + l] = fmaxf(h, 0.f);
        }
        #pragma unroll 8
        for (int j = 0; j < 32; ++j)
            dec_in[(size_t)(96 + j) * 4096 + bBase + l] = x_s[l * 768 + (64 + j) * 8];
    }
}

// ============ K3: decoder fused: d1 LSTM(1->16) + d2(H=1) + fc1 + fc2 ============
__global__ __launch_bounds__(256, 2) void k3_dec(
    const float* __restrict__ dec_in,
    const float* __restrict__ d1_Wih, const float* __restrict__ d1_Whh, const float* __restrict__ d1_b,
    const float* __restrict__ d2_Wih, const float* __restrict__ d2_b,
    const float* __restrict__ d2_Whh,
    const float* __restrict__ fc1_W, const float* __restrict__ fc1_b,
    const float* __restrict__ fc2_W, const float* __restrict__ fc2_b,
    float* __restrict__ out)
{
    __shared__ float din_s[16 * 129];
    __shared__ float h_lds[16][16];
    __shared__ float pd2_s[16 * 516];
    __shared__ float d2h_s[16 * 132];
    __shared__ float mid_s[16 * 36];

    const int t = threadIdx.x;
    const int w = t >> 6, lane = t & 63;
    const int qq4 = lane >> 4, u = lane & 15;
    const int row = w * 4 + qq4;
    const size_t bBase = (size_t)blockIdx.x * 16;

    for (int i = t; i < 2048; i += 256) {
        int ts = i >> 4, rr = i & 15;
        din_s[rr * 129 + ts] = dec_in[(size_t)ts * 4096 + bBase + rr];
    }

    float wih_g[4], bg[4], whh_g[4][16], d2w[16];
    #pragma unroll
    for (int g = 0; g < 4; ++g) {
        wih_g[g] = d1_Wih[g * 16 + u];
        bg[g]    = d1_b[g * 16 + u];
        const float4* wp = (const float4*)(d1_Whh + (size_t)(g * 16 + u) * 16);
        #pragma unroll
        for (int k4 = 0; k4 < 4; ++k4) {
            float4 v = wp[k4];
            whh_g[g][4*k4+0] = v.x; whh_g[g][4*k4+1] = v.y;
            whh_g[g][4*k4+2] = v.z; whh_g[g][4*k4+3] = v.w;
        }
    }
    {
        const float4* wp = (const float4*)(d2_Wih + (size_t)(u & 3) * 16);
        #pragma unroll
        for (int k4 = 0; k4 < 4; ++k4) {
            float4 v = wp[k4];
            d2w[4*k4+0] = v.x; d2w[4*k4+1] = v.y; d2w[4*k4+2] = v.z; d2w[4*k4+3] = v.w;
        }
    }
    const float d2bias = d2_b[u & 3];

    float h = 0.f, c = 0.f;
    __syncthreads();

    float hv[16];
    for (int ts = 0; ts < 128; ++ts) {
        float xv = din_s[row * 129 + ts];
        float p0 = fmaf(xv, wih_g[0], bg[0]);
        float p1 = fmaf(xv, wih_g[1], bg[1]);
        float p2 = fmaf(xv, wih_g[2], bg[2]);
        float p3 = fmaf(xv, wih_g[3], bg[3]);
        if (ts > 0) {
            const float4* hp = (const float4*)&h_lds[row][0];
            #pragma unroll
            for (int k4 = 0; k4 < 4; ++k4) {
                float4 v = hp[k4];
                hv[4*k4+0] = v.x; hv[4*k4+1] = v.y; hv[4*k4+2] = v.z; hv[4*k4+3] = v.w;
            }
            #pragma unroll
            for (int k = 0; k < 16; ++k) {
                p0 = fmaf(hv[k], whh_g[0][k], p0);
                p1 = fmaf(hv[k], whh_g[1][k], p1);
                p2 = fmaf(hv[k], whh_g[2][k], p2);
                p3 = fmaf(hv[k], whh_g[3][k], p3);
            }
            if (u < 4) {
                float a = d2bias;
                #pragma unroll
                for (int k = 0; k < 16; ++k) a = fmaf(hv[k], d2w[k], a);
                pd2_s[row * 516 + (ts - 1) * 4 + u] = a;
            }
        }
        c = fmaf(sigm(p1), c, sigm(p0) * tanh_(p2));
        h = sigm(p3) * tanh_(c);
        h_lds[row][u] = h;
    }
    {
        const float4* hp = (const float4*)&h_lds[row][0];
        #pragma unroll
        for (int k4 = 0; k4 < 4; ++k4) {
            float4 v = hp[k4];
            hv[4*k4+0] = v.x; hv[4*k4+1] = v.y; hv[4*k4+2] = v.z; hv[4*k4+3] = v.w;
        }
        if (u < 4) {
            float a = d2bias;
            #pragma unroll
            for (int k = 0; k < 16; ++k) a = fmaf(hv[k], d2w[k], a);
            pd2_s[row * 516 + 127 * 4 + u] = a;
        }
    }
    __syncthreads();

    // ---- d2 recurrence: 16 lanes, depth-4 register prefetch ----
    {
        const float w0 = d2_Whh[0], w1 = d2_Whh[1], w2 = d2_Whh[2], w3 = d2_Whh[3];
        if (t < 16) {
            float4 dbuf[4];
            #pragma unroll
            for (int j = 0; j < 4; ++j) dbuf[j] = *(const float4*)&pd2_s[t * 516 + j * 4];
            float h2 = 0.f, c2 = 0.f;
            #pragma unroll
            for (int ts = 0; ts < 128; ++ts) {
                float4 g4 = dbuf[ts & 3];
                if (ts + 4 < 128) dbuf[ts & 3] = *(const float4*)&pd2_s[t * 516 + (ts + 4) * 4];
                float gi = fmaf(h2, w0, g4.x);
                float gf = fmaf(h2, w1, g4.y);
                float gg = fmaf(h2, w2, g4.z);
                float go = fmaf(h2, w3, g4.w);
                c2 = fmaf(sigm(gf), c2, sigm(gi) * tanh_(gg));
                h2 = sigm(go) * tanh_(c2);
                d2h_s[t * 132 + ts] = h2;
            }
        }
    }
    __syncthreads();

    // ---- fc1 (128->32) + fc2 (32->32) ----
    {
        const int bb = t >> 4, o = t & 15;
        float acc0 = fc1_b[o], acc1 = fc1_b[o + 16];
        const float4* wa = (const float4*)(fc1_W + (size_t)o * 128);
        const float4* wb = (const float4*)(fc1_W + (size_t)(o + 16) * 128);
        const float4* fp = (const float4*)&d2h_s[bb * 132];
        #pragma unroll
        for (int k4 = 0; k4 < 32; ++k4) {
            float4 f = fp[k4], va = wa[k4], vb = wb[k4];
            acc0 = fmaf(f.x, va.x, acc0); acc0 = fmaf(f.y, va.y, acc0);
            acc0 = fmaf(f.z, va.z, acc0); acc0 = fmaf(f.w, va.w, acc0);
            acc1 = fmaf(f.x, vb.x, acc1); acc1 = fmaf(f.y, vb.y, acc1);
            acc1 = fmaf(f.z, vb.z, acc1); acc1 = fmaf(f.w, vb.w, acc1);
        }
        mid_s[bb * 36 + o] = acc0;
        mid_s[bb * 36 + o + 16] = acc1;
        __syncthreads();
        float o0 = fc2_b[o], o1 = fc2_b[o + 16];
        const float4* va2 = (const float4*)(fc2_W + (size_t)o * 32);
        const float4* vb2 = (const float4*)(fc2_W + (size_t)(o + 16) * 32);
        const float4* mp = (const float4*)&mid_s[bb * 36];
        #pragma unroll
        for (int k4 = 0; k4 < 8; ++k4) {
            float4 m = mp[k4], va = va2[k4], vb = vb2[k4];
            o0 = fmaf(m.x, va.x, o0); o0 = fmaf(m.y, va.y, o0);
            o0 = fmaf(m.z, va.z, o0); o0 = fmaf(m.w, va.w, o0);
            o1 = fmaf(m.x, vb.x, o1); o1 = fmaf(m.y, vb.y, o1);
            o1 = fmaf(m.z, vb.z, o1); o1 = fmaf(m.w, vb.w, o1);
        }
        out[(bBase + bb) * 32 + o] = o0;
        out[(bBase + bb) * 32 + o + 16] = o1;
    }
}

extern "C" void kernel_launch(void* const* d_in, const int* in_sizes, int n_in,
                              void* d_out, int out_size, void* d_ws, size_t ws_size,
                              hipStream_t stream) {
    const float* x      = (const float*)d_in[0];
    const float* e1_Wih = (const float*)d_in[1];
    const float* e1_Whh = (const float*)d_in[2];
    const float* e1_b   = (const float*)d_in[3];
    const float* e2_Wih = (const float*)d_in[4];
    const float* e2_Whh = (const float*)d_in[5];
    const float* e2_b   = (const float*)d_in[6];
    const float* d1_Wih = (const float*)d_in[7];
    const float* d1_Whh = (const float*)d_in[8];
    const float* d1_b   = (const float*)d_in[9];
    const float* d2_Wih = (const float*)d_in[10];
    const float* d2_Whh = (const float*)d_in[11];
    const float* d2_b   = (const float*)d_in[12];
    const float* fc1_W  = (const float*)d_in[13];
    const float* fc1_b  = (const float*)d_in[14];
    const float* fc2_W  = (const float*)d_in[15];
    const float* fc2_b  = (const float*)d_in[16];
    float* out = (float*)d_out;

    float* dec_in = (float*)d_ws;       // [128][4096]

    hipLaunchKernelGGL(k1_enc, dim3(512), dim3(512), 0, stream,
                       x, e1_Wih, e1_Whh, e1_b, e2_Wih, e2_b, e2_Whh, dec_in);
    hipLaunchKernelGGL(k3_dec, dim3(256), dim3(256), 0, stream,
                       dec_in, d1_Wih, d1_Whh, d1_b, d2_Wih, d2_b, d2_Whh,
                       fc1_W, fc1_b, fc2_W, fc2_b, out);
}

// Round 9
// 228.693 us; speedup vs baseline: 1.0065x; 1.0065x over previous
//
#include <hip/hip_runtime.h>
#include <hip/hip_bf16.h>

typedef __attribute__((ext_vector_type(8))) short bf16x8;
typedef __attribute__((ext_vector_type(4))) float f32x4;

__device__ __forceinline__ float sigm(float x) {
    return __builtin_amdgcn_rcpf(1.0f + __expf(-x));
}
__device__ __forceinline__ float tanh_(float x) {
    float e = __expf(2.0f * x);
    return 1.0f - 2.0f * __builtin_amdgcn_rcpf(e + 1.0f);
}
__device__ __forceinline__ ushort f2bf(float f) {   // RNE float->bf16
    uint u = __float_as_uint(f);
    u = u + 0x7FFFu + ((u >> 16) & 1u);
    return (ushort)(u >> 16);
}
__device__ __forceinline__ float bf2f(ushort s) { return __uint_as_float(((uint)s) << 16); }
__device__ __forceinline__ float sel4(f32x4 a, int k) {
    float lo = (k & 1) ? a[1] : a[0];
    float hi = (k & 1) ? a[3] : a[2];
    return (k & 2) ? hi : lo;
}
__device__ __forceinline__ float sel4v(float a0, float a1, float a2, float a3, int s) {
    float lo = (s & 1) ? a1 : a0;
    float hi = (s & 1) ? a3 : a2;
    return (s & 2) ? hi : lo;
}

// ============ K1: e1 LSTM(8->64) via MFMA, 16 waves x 1 tile, fused e2 ============
// 16 batches/block, 1024 threads (16 waves), grid 256. Wave T owns tile T
// (units 4T..4T+3 x 4 gates); wave 0 additionally owns the e2-xg tile.
// h stored in A-FRAGMENT-LINEAR layout: lane l reads bytes [16l,16l+16) ->
// dense contiguous wave read (no bank conflicts; R6/R7 strided rows cost 4-8M
// conflict cycles). Activation applied BEFORE the quad transpose (4 parallel
// transcendentals + 1 serial instead of 5 serial). One barrier/step.
// e2 recurrence fused at tail (16 lanes of wave 0); dec_in written directly.
__global__ __launch_bounds__(1024) __attribute__((amdgpu_waves_per_eu(4, 4)))
void k1_enc(
    const float* __restrict__ x,
    const float* __restrict__ e1_Wih, const float* __restrict__ e1_Whh, const float* __restrict__ e1_b,
    const float* __restrict__ e2_Wih, const float* __restrict__ e2_b,
    const float* __restrict__ e2_Whh,
    float* __restrict__ dec_in)   // [ts][4096]
{
    __shared__ float x_s[16 * 768];                   // 48 KB
    __shared__ __align__(16) ushort h_hi[2 * 2 * 512];   // [parity][chunk][lane*8] 4 KB
    __shared__ __align__(16) ushort h_lo[2 * 2 * 512];   // 4 KB
    __shared__ __align__(16) ushort x2_s[2 * 512];       // 2 KB
    __shared__ __align__(16) float pe2_s[96 * 4 * 16];   // [ts][g][batch] 24 KB

    const int t = threadIdx.x;
    const int bBase = blockIdx.x * 16;
    const int wv = t >> 6, l = t & 63;
    const int q = l & 15, sub = l >> 4;
    const int u_loc = q >> 2, g = q & 3;

    // ---- stage x ----
    for (int i = t; i < 16 * 768; i += 1024) x_s[i] = x[(size_t)bBase * 768 + i];

    // ---- weight fragments (hi/lo bf16) ----
    auto loadW = [&](const float* rowbase, int k0, bool valid, bf16x8& hi8, bf16x8& lo8) {
        float f[8];
        if (valid) {
            float4 v0 = ((const float4*)(rowbase + k0))[0];
            float4 v1 = ((const float4*)(rowbase + k0))[1];
            f[0]=v0.x; f[1]=v0.y; f[2]=v0.z; f[3]=v0.w;
            f[4]=v1.x; f[5]=v1.y; f[6]=v1.z; f[7]=v1.w;
        } else {
            #pragma unroll
            for (int j = 0; j < 8; ++j) f[j] = 0.f;
        }
        #pragma unroll
        for (int j = 0; j < 8; ++j) {
            ushort h = f2bf(f[j]);
            hi8[j] = (short)h;
            lo8[j] = (short)f2bf(f[j] - bf2f(h));
        }
    };
    auto loadTileB = [&](int T, bool isE2, bf16x8& Bh0, bf16x8& Bh1, bf16x8& Bl0, bf16x8& Bl1, bf16x8& B2) {
        const bool valid = !isE2 || (u_loc == 0);
        const int wrow = isE2 ? g : (g * 64 + T * 4 + u_loc);
        const float* rowp = isE2 ? (e2_Wih + (size_t)wrow * 64) : (e1_Whh + (size_t)wrow * 64);
        loadW(rowp, sub * 8,      valid, Bh0, Bl0);
        loadW(rowp, 32 + sub * 8, valid, Bh1, Bl1);
        #pragma unroll
        for (int j = 0; j < 8; ++j) B2[j] = 0;
        if (!isE2) {
            if (sub < 3) {       // k 0-7: Wih_hi(*xhi), 8-15: Wih_hi(*xlo), 16-23: Wih_lo(*xhi)
                const float* wr = e1_Wih + (size_t)wrow * 8;
                #pragma unroll
                for (int j = 0; j < 8; ++j) {
                    float f = wr[j];
                    ushort h = f2bf(f);
                    B2[j] = (sub < 2) ? (short)h : (short)f2bf(f - bf2f(h));
                }
            } else {             // k 24,25: bias hi/lo (A2 = 1.0 there)
                float bb = e1_b[wrow];
                ushort h = f2bf(bb);
                B2[0] = (short)h; B2[1] = (short)f2bf(bb - bf2f(h));
            }
        } else if (valid && sub == 3) {
            float bb = e2_b[g];
            ushort h = f2bf(bb);
            B2[0] = (short)h; B2[1] = (short)f2bf(bb - bf2f(h));
        }
    };

    bf16x8 B0h0, B0h1, B0l0, B0l1, B0x;
    bf16x8 B2h0, B2h1, B2l0, B2l1, B2x;
    loadTileB(wv, false, B0h0, B0h1, B0l0, B0l1, B0x);
    if (wv == 0) loadTileB(0, true, B2h0, B2h1, B2l0, B2l1, B2x);

    __syncthreads();   // x_s ready

    // ---- init: h parity0 = 0; x2 both parities ----
    h_hi[t] = 0; h_lo[t] = 0;         // t<1024 covers parity0's 1024 entries
    if (t < 512) {
        int sb = t >> 7, j = t & 7, B = (t >> 3) & 15;
        int k = sb * 8 + j;
        ushort v0, v1;
        if (k < 24) {
            float xv = x_s[B * 768 + j];
            ushort hi = f2bf(xv);
            v0 = (sb == 1) ? f2bf(xv - bf2f(hi)) : hi;
            v1 = 0;
        } else {
            v0 = v1 = (k == 24 || k == 25) ? (ushort)0x3F80 : (ushort)0;
        }
        x2_s[t] = v0; x2_s[512 + t] = v1;
    }

    // h-write index (lane-const): element (B=4sub+g, U=4*wv+u_loc)
    const int h_wfull = (wv >> 3) * 512 + ((wv & 7) >> 1) * 128 + (4 * sub + g) * 8 + (wv & 1) * 4 + u_loc;
    // gate-activation constants: tanh(x) = 2*sigm(2x)-1
    const float a_sc = (g == 2) ? 2.f : 1.f;
    const float a_m  = (g == 2) ? 2.f : 1.f;
    const float a_b  = (g == 2) ? -1.f : 0.f;

    float c_r = 0.f;
    __syncthreads();

    #pragma unroll 1
    for (int ts = 0; ts < 96; ++ts) {
        const int p = ts & 1, pn = p ^ 1;
        const int pb = p * 1024;

        // A fragments: dense contiguous reads (lane l -> bytes [16l,16l+16))
        bf16x8 Ah0 = *(const bf16x8*)&h_hi[pb + l * 8];
        bf16x8 Ah1 = *(const bf16x8*)&h_hi[pb + 512 + l * 8];
        bf16x8 Al0 = *(const bf16x8*)&h_lo[pb + l * 8];
        bf16x8 Al1 = *(const bf16x8*)&h_lo[pb + 512 + l * 8];
        bf16x8 A2v = *(const bf16x8*)&x2_s[p * 512 + l * 8];

        f32x4 a0 = {0.f,0.f,0.f,0.f}, e0 = {0.f,0.f,0.f,0.f};
        a0 = __builtin_amdgcn_mfma_f32_16x16x32_bf16(Ah0, B0h0, a0, 0, 0, 0);
        a0 = __builtin_amdgcn_mfma_f32_16x16x32_bf16(Al0, B0h0, a0, 0, 0, 0);
        a0 = __builtin_amdgcn_mfma_f32_16x16x32_bf16(Ah0, B0l0, a0, 0, 0, 0);
        e0 = __builtin_amdgcn_mfma_f32_16x16x32_bf16(Ah1, B0h1, e0, 0, 0, 0);
        e0 = __builtin_amdgcn_mfma_f32_16x16x32_bf16(Al1, B0h1, e0, 0, 0, 0);
        e0 = __builtin_amdgcn_mfma_f32_16x16x32_bf16(Ah1, B0l1, e0, 0, 0, 0);
        e0 = __builtin_amdgcn_mfma_f32_16x16x32_bf16(A2v, B0x,  e0, 0, 0, 0);

        if (wv == 0) {   // e2 xg tile: uses h entering this step -> pe2[ts-1]
            f32x4 a2 = {0.f,0.f,0.f,0.f}, e2 = {0.f,0.f,0.f,0.f};
            a2 = __builtin_amdgcn_mfma_f32_16x16x32_bf16(Ah0, B2h0, a2, 0, 0, 0);
            a2 = __builtin_amdgcn_mfma_f32_16x16x32_bf16(Al0, B2h0, a2, 0, 0, 0);
            a2 = __builtin_amdgcn_mfma_f32_16x16x32_bf16(Ah0, B2l0, a2, 0, 0, 0);
            e2 = __builtin_amdgcn_mfma_f32_16x16x32_bf16(Ah1, B2h1, e2, 0, 0, 0);
            e2 = __builtin_amdgcn_mfma_f32_16x16x32_bf16(Al1, B2h1, e2, 0, 0, 0);
            e2 = __builtin_amdgcn_mfma_f32_16x16x32_bf16(Ah1, B2l1, e2, 0, 0, 0);
            e2 = __builtin_amdgcn_mfma_f32_16x16x32_bf16(A2v, B2x,  e2, 0, 0, 0);
            if (ts > 0 && q < 4) {
                f32x4 acc2 = a2 + e2;
                *(float4*)&pe2_s[(ts - 1) * 64 + q * 16 + 4 * sub] =
                    make_float4(acc2[0], acc2[1], acc2[2], acc2[3]);
            }
        }

        // ---- activation BEFORE transpose ----
        {
            f32x4 acc = a0 + e0;
            f32x4 actv;
            #pragma unroll
            for (int i2 = 0; i2 < 4; ++i2)
                actv[i2] = fmaf(a_m, sigm(a_sc * acc[i2]), a_b);
            float own = sel4(actv, g);
            float r1 = __shfl_xor(sel4(actv, g ^ 1), 1);
            float r2 = __shfl_xor(sel4(actv, g ^ 2), 2);
            float r3 = __shfl_xor(sel4(actv, g ^ 3), 3);
            float i_ = sel4v(own, r1, r2, r3, g);
            float f_ = sel4v(own, r1, r2, r3, g ^ 1);
            float g_ = sel4v(own, r1, r2, r3, g ^ 2);
            float o_ = sel4v(own, r1, r2, r3, g ^ 3);
            c_r = fmaf(f_, c_r, i_ * g_);
            float hv = o_ * tanh_(c_r);
            ushort hh = f2bf(hv);
            h_hi[pn * 1024 + h_wfull] = hh;
            h_lo[pn * 1024 + h_wfull] = f2bf(hv - bf2f(hh));
        }

        if (ts < 95 && t < 384) {   // build x2[pn] for ts+1
            int sb = t >> 7, j = t & 7, B = (t >> 3) & 15;
            float xv = x_s[B * 768 + (ts + 1) * 8 + j];
            ushort hi = f2bf(xv);
            x2_s[pn * 512 + t] = (sb == 1) ? f2bf(xv - bf2f(hi)) : hi;
        }
        __syncthreads();
    }

    // ---- pe2[95] from final h (parity 0) ----
    if (wv == 0) {
        bf16x8 Ah0 = *(const bf16x8*)&h_hi[l * 8];
        bf16x8 Ah1 = *(const bf16x8*)&h_hi[512 + l * 8];
        bf16x8 Al0 = *(const bf16x8*)&h_lo[l * 8];
        bf16x8 Al1 = *(const bf16x8*)&h_lo[512 + l * 8];
        bf16x8 A2v = *(const bf16x8*)&x2_s[l * 8];   // only k=24,25 matter (bias)
        f32x4 a2 = {0.f,0.f,0.f,0.f}, e2 = {0.f,0.f,0.f,0.f};
        a2 = __builtin_amdgcn_mfma_f32_16x16x32_bf16(Ah0, B2h0, a2, 0, 0, 0);
        a2 = __builtin_amdgcn_mfma_f32_16x16x32_bf16(Al0, B2h0, a2, 0, 0, 0);
        a2 = __builtin_amdgcn_mfma_f32_16x16x32_bf16(Ah0, B2l0, a2, 0, 0, 0);
        e2 = __builtin_amdgcn_mfma_f32_16x16x32_bf16(Ah1, B2h1, e2, 0, 0, 0);
        e2 = __builtin_amdgcn_mfma_f32_16x16x32_bf16(Al1, B2h1, e2, 0, 0, 0);
        e2 = __builtin_amdgcn_mfma_f32_16x16x32_bf16(Ah1, B2l1, e2, 0, 0, 0);
        e2 = __builtin_amdgcn_mfma_f32_16x16x32_bf16(A2v, B2x,  e2, 0, 0, 0);
        if (q < 4) {
            f32x4 acc2 = a2 + e2;
            *(float4*)&pe2_s[95 * 64 + q * 16 + 4 * sub] =
                make_float4(acc2[0], acc2[1], acc2[2], acc2[3]);
        }
    }

    // ---- fused e2 recurrence: wave 0, lane = batch, 1-deep prefetch ----
    if (wv == 0 && l < 16) {
        const float w0 = e2_Whh[0], w1 = e2_Whh[1], w2 = e2_Whh[2], w3 = e2_Whh[3];
        float ni = pe2_s[l], nf = pe2_s[16 + l], ng = pe2_s[32 + l], no = pe2_s[48 + l];
        float h = 0.f, c = 0.f;
        #pragma unroll 1
        for (int ts = 0; ts < 96; ++ts) {
            float gi = ni, gf = nf, gg2 = ng, go = no;
            if (ts < 95) {
                int b2 = (ts + 1) * 64;
                ni = pe2_s[b2 + l]; nf = pe2_s[b2 + 16 + l];
                ng = pe2_s[b2 + 32 + l]; no = pe2_s[b2 + 48 + l];
            }
            gi = fmaf(h, w0, gi);
            gf = fmaf(h, w1, gf);
            gg2 = fmaf(h, w2, gg2);
            go = fmaf(h, w3, go);
            c = fmaf(sigm(gf), c, sigm(gi) * tanh_(gg2));
            h = sigm(go) * tanh_(c);
            dec_in[(size_t)ts * 4096 + bBase + l] = fmaxf(h, 0.f);
        }
    }
    // ---- x_aux rows (waves 1-8) ----
    if (wv >= 1 && wv <= 8) {
        int i = (wv - 1) * 64 + l;
        int B = i >> 5, j = i & 31;
        dec_in[(size_t)(96 + j) * 4096 + bBase + B] = x_s[B * 768 + (64 + j) * 8];
    }
}

// ============ K3: decoder, wave-per-batch: d1(1->16) + d2(H=1) + fc1 + fc2 ============
// grid 512 x 512 threads (8 waves = 8 batches/block) -> 2 blocks/CU, 16 waves/CU.
// Lane (u = l>>2, g = l&3): one gate-row of unit u. Gates exchanged via quad
// shfl_xor; d2-xg via 4-step shfl reduce over u. ZERO barriers after staging
// (everything wave-local).
__global__ __launch_bounds__(512) __attribute__((amdgpu_waves_per_eu(4, 4)))
void k3_dec(
    const float* __restrict__ dec_in,
    const float* __restrict__ d1_Wih, const float* __restrict__ d1_Whh, const float* __restrict__ d1_b,
    const float* __restrict__ d2_Wih, const float* __restrict__ d2_b,
    const float* __restrict__ d2_Whh,
    const float* __restrict__ fc1_W, const float* __restrict__ fc1_b,
    const float* __restrict__ fc2_W, const float* __restrict__ fc2_b,
    float* __restrict__ out)
{
    __shared__ float din_s[8 * 132];     // [w][ts]
    __shared__ float h_s[8][16];
    __shared__ float pd2_s[8 * 520];     // [w][ts*4+g]
    __shared__ float d2h_s[8 * 132];     // [w][ts]
    __shared__ float mid_s[8 * 36];      // [w][o]

    const int t = threadIdx.x;
    const int w = t >> 6, l = t & 63;
    const int u = l >> 2, g = l & 3;
    const size_t bBase = (size_t)blockIdx.x * 8;

    for (int i = t; i < 1024; i += 512) {
        int ts = i >> 3, bb = i & 7;
        din_s[bb * 132 + ts] = dec_in[(size_t)ts * 4096 + bBase + bb];
    }

    const int row = g * 16 + u;
    const float wih1 = d1_Wih[row], b1 = d1_b[row];
    float whh[16];
    {
        const float4* wp = (const float4*)(d1_Whh + (size_t)row * 16);
        #pragma unroll
        for (int k4 = 0; k4 < 4; ++k4) {
            float4 v = wp[k4];
            whh[4*k4+0] = v.x; whh[4*k4+1] = v.y; whh[4*k4+2] = v.z; whh[4*k4+3] = v.w;
        }
    }
    const float d2wi = d2_Wih[g * 16 + u];
    const float d2b = (l < 4) ? d2_b[g] : 0.f;
    const float a_sc = (g == 2) ? 2.f : 1.f;
    const float a_m  = (g == 2) ? 2.f : 1.f;
    const float a_b  = (g == 2) ? -1.f : 0.f;

    float c1v = 0.f;
    __syncthreads();

    // ---- d1 + fused d2-xg: 128 steps, wave-synchronous ----
    #pragma unroll 1
    for (int ts = 0; ts < 128; ++ts) {
        float xv = din_s[w * 132 + ts];
        float p = fmaf(xv, wih1, b1);
        if (ts > 0) {
            const float4* hp = (const float4*)&h_s[w][0];
            #pragma unroll
            for (int k4 = 0; k4 < 4; ++k4) {
                float4 v = hp[k4];
                p = fmaf(v.x, whh[4*k4+0], p); p = fmaf(v.y, whh[4*k4+1], p);
                p = fmaf(v.z, whh[4*k4+2], p); p = fmaf(v.w, whh[4*k4+3], p);
            }
        }
        float a = fmaf(a_m, sigm(a_sc * p), a_b);     // gate-g activation
        float r1 = __shfl_xor(a, 1), r2 = __shfl_xor(a, 2), r3 = __shfl_xor(a, 3);
        float i_ = sel4v(a, r1, r2, r3, g);
        float f_ = sel4v(a, r1, r2, r3, g ^ 1);
        float g_ = sel4v(a, r1, r2, r3, g ^ 2);
        float o_ = sel4v(a, r1, r2, r3, g ^ 3);
        c1v = fmaf(f_, c1v, i_ * g_);
        float hh = o_ * tanh_(c1v);
        // fused d2 xg: sum h[u]*d2_Wih[g][u] over u (shfl reduce over u-bits)
        float s = hh * d2wi;
        s += __shfl_xor(s, 4); s += __shfl_xor(s, 8);
        s += __shfl_xor(s, 16); s += __shfl_xor(s, 32);
        if (l < 4) pd2_s[w * 520 + ts * 4 + g] = s + d2b;
        if (g == 0) h_s[w][u] = hh;
    }

    // ---- d2 recurrence: lane 0 per wave, 1-deep prefetch ----
    if (l == 0) {
        const float w0 = d2_Whh[0], w1 = d2_Whh[1], w2 = d2_Whh[2], w3 = d2_Whh[3];
        float4 nxt = *(const float4*)&pd2_s[w * 520];
        float h2 = 0.f, c2 = 0.f;
        #pragma unroll 1
        for (int ts2 = 0; ts2 < 128; ++ts2) {
            float4 cur = nxt;
            if (ts2 < 127) nxt = *(const float4*)&pd2_s[w * 520 + (ts2 + 1) * 4];
            float gi = fmaf(h2, w0, cur.x);
            float gf = fmaf(h2, w1, cur.y);
            float gg = fmaf(h2, w2, cur.z);
            float go = fmaf(h2, w3, cur.w);
            c2 = fmaf(sigm(gf), c2, sigm(gi) * tanh_(gg));
            h2 = sigm(go) * tanh_(c2);
            d2h_s[w * 132 + ts2] = h2;
        }
    }

    // ---- fc1 (128->32) + fc2 (32->32): lanes 0-31, wave-local ----
    if (l < 32) {
        float acc = fc1_b[l];
        const float4* wp = (const float4*)(fc1_W + (size_t)l * 128);
        const float4* fp = (const float4*)&d2h_s[w * 132];
        #pragma unroll
        for (int k4 = 0; k4 < 32; ++k4) {
            float4 f = fp[k4], vv = wp[k4];
            acc = fmaf(f.x, vv.x, acc); acc = fmaf(f.y, vv.y, acc);
            acc = fmaf(f.z, vv.z, acc); acc = fmaf(f.w, vv.w, acc);
        }
        mid_s[w * 36 + l] = acc;
        float o2 = fc2_b[l];
        const float4* w2p = (const float4*)(fc2_W + (size_t)l * 32);
        const float4* mp = (const float4*)&mid_s[w * 36];
        #pragma unroll
        for (int k4 = 0; k4 < 8; ++k4) {
            float4 m = mp[k4], vv = w2p[k4];
            o2 = fmaf(m.x, vv.x, o2); o2 = fmaf(m.y, vv.y, o2);
            o2 = fmaf(m.z, vv.z, o2); o2 = fmaf(m.w, vv.w, o2);
        }
        out[(bBase + w) * 32 + l] = o2;
    }
}

extern "C" void kernel_launch(void* const* d_in, const int* in_sizes, int n_in,
                              void* d_out, int out_size, void* d_ws, size_t ws_size,
                              hipStream_t stream) {
    const float* x      = (const float*)d_in[0];
    const float* e1_Wih = (const float*)d_in[1];
    const float* e1_Whh = (const float*)d_in[2];
    const float* e1_b   = (const float*)d_in[3];
    const float* e2_Wih = (const float*)d_in[4];
    const float* e2_Whh = (const float*)d_in[5];
    const float* e2_b   = (const float*)d_in[6];
    const float* d1_Wih = (const float*)d_in[7];
    const float* d1_Whh = (const float*)d_in[8];
    const float* d1_b   = (const float*)d_in[9];
    const float* d2_Wih = (const float*)d_in[10];
    const float* d2_Whh = (const float*)d_in[11];
    const float* d2_b   = (const float*)d_in[12];
    const float* fc1_W  = (const float*)d_in[13];
    const float* fc1_b  = (const float*)d_in[14];
    const float* fc2_W  = (const float*)d_in[15];
    const float* fc2_b  = (const float*)d_in[16];
    float* out = (float*)d_out;

    float* dec_in = (float*)d_ws;       // [128][4096]

    hipLaunchKernelGGL(k1_enc, dim3(256), dim3(1024), 0, stream,
                       x, e1_Wih, e1_Whh, e1_b, e2_Wih, e2_b, e2_Whh, dec_in);
    hipLaunchKernelGGL(k3_dec, dim3(512), dim3(512), 0, stream,
                       dec_in, d1_Wih, d1_Whh, d1_b, d2_Wih, d2_b, d2_Whh,
                       fc1_W, fc1_b, fc2_W, fc2_b, out);
}

// Round 10
// 158.382 us; speedup vs baseline: 1.4534x; 1.4439x over previous
//
#include <hip/hip_runtime.h>
#include <hip/hip_bf16.h>

typedef __attribute__((ext_vector_type(8))) short bf16x8;
typedef __attribute__((ext_vector_type(4))) float f32x4;

__device__ __forceinline__ float sigm(float x) {
    return __builtin_amdgcn_rcpf(1.0f + __expf(-x));
}
__device__ __forceinline__ float tanh_(float x) {
    float e = __expf(2.0f * x);
    return 1.0f - 2.0f * __builtin_amdgcn_rcpf(e + 1.0f);
}
__device__ __forceinline__ ushort f2bf(float f) {   // RNE float->bf16
    uint u = __float_as_uint(f);
    u = u + 0x7FFFu + ((u >> 16) & 1u);
    return (ushort)(u >> 16);
}
__device__ __forceinline__ float bf2f(ushort s) { return __uint_as_float(((uint)s) << 16); }

// ============ K1: e1 LSTM via MFMA with SWAPPED OPERANDS (A=weights, B=h) ============
// 16 batches/block, 512 threads (8 waves), grid 256. Wave wv owns tiles 2wv,2wv+1;
// wave 7 additionally owns the e2-xg tile.
// A = weight fragments: loop-invariant, VGPR-resident (no weight LDS reads/step).
// A rows unit-major (row r = gate (r&3) of unit (r>>2)) so the C fragment gives
// each lane acc[0..3] = (i,f,g,o) of ONE (batch = lane&15, unit = T*4 + lane>>4):
// the LSTM cell is computed straight from the accumulator — NO transpose, no
// sel4/shfl chains (R5-R8 burned ~300 VALU/wave-step on that; this is the fix).
// B = h fragments from blocked LDS h[sub][batch][8]: 5 dense conflict-free b128
// reads per step, SHARED by both tiles. e2 recurrence fused at tail.
__global__ __launch_bounds__(512) __attribute__((amdgpu_waves_per_eu(2, 2)))
void k1_enc(
    const float* __restrict__ x,
    const float* __restrict__ e1_Wih, const float* __restrict__ e1_Whh, const float* __restrict__ e1_b,
    const float* __restrict__ e2_Wih, const float* __restrict__ e2_b,
    const float* __restrict__ e2_Whh,
    float* __restrict__ dec_in)   // [ts][4096]
{
    __shared__ float x_s[16 * 772];                      // rows padded to 772 (2-way banks)
    __shared__ __align__(16) ushort h_hi[2][8][16][8];   // [parity][u-blk][batch][j] 4 KB
    __shared__ __align__(16) ushort h_lo[2][8][16][8];   // 4 KB
    __shared__ __align__(16) ushort x2_s[2][4][16][8];   // 2 KB
    __shared__ __align__(16) float pe2_s[96 * 64];       // [ts][gate][batch] 24 KB

    const int t = threadIdx.x;
    const int bBase = blockIdx.x * 16;
    const int wv = t >> 6, l = t & 63;
    const int row = l & 15, sub = l >> 4;    // A-side: gate-row, k-chunk; B/C-side: batch=l&15

    // ---- stage x ----
    for (int bb = 0; bb < 16; ++bb)
        for (int i = t; i < 768; i += 512)
            x_s[bb * 772 + i] = x[(size_t)(bBase + bb) * 768 + i];

    // ---- A fragments (weights, hi/lo bf16) — loop-invariant ----
    auto loadW = [&](const float* rowbase, int k0, bool valid, bf16x8& hi8, bf16x8& lo8) {
        float f[8];
        if (valid) {
            float4 v0 = ((const float4*)(rowbase + k0))[0];
            float4 v1 = ((const float4*)(rowbase + k0))[1];
            f[0]=v0.x; f[1]=v0.y; f[2]=v0.z; f[3]=v0.w;
            f[4]=v1.x; f[5]=v1.y; f[6]=v1.z; f[7]=v1.w;
        } else {
            #pragma unroll
            for (int j = 0; j < 8; ++j) f[j] = 0.f;
        }
        #pragma unroll
        for (int j = 0; j < 8; ++j) {
            ushort h = f2bf(f[j]);
            hi8[j] = (short)h;
            lo8[j] = (short)f2bf(f[j] - bf2f(h));
        }
    };
    auto loadA = [&](int T, bool isE2, bf16x8& Ah0, bf16x8& Ah1, bf16x8& Al0, bf16x8& Al1, bf16x8& A2) {
        const int gate = row & 3, uq = row >> 2;
        const bool valid = !isE2 || (uq == 0);
        const int wr = isE2 ? gate : gate * 64 + T * 4 + uq;
        const float* rp = isE2 ? (e2_Wih + (size_t)wr * 64) : (e1_Whh + (size_t)wr * 64);
        loadW(rp, sub * 8,      valid, Ah0, Al0);
        loadW(rp, 32 + sub * 8, valid, Ah1, Al1);
        #pragma unroll
        for (int j = 0; j < 8; ++j) A2[j] = 0;
        if (valid) {
            if (!isE2) {
                if (sub < 3) {   // k0-7: Wih_hi(*xhi), 8-15: Wih_hi(*xlo), 16-23: Wih_lo(*xhi)
                    const float* wihr = e1_Wih + (size_t)wr * 8;
                    #pragma unroll
                    for (int j = 0; j < 8; ++j) {
                        float f = wihr[j];
                        ushort hh = f2bf(f);
                        A2[j] = (sub < 2) ? (short)hh : (short)f2bf(f - bf2f(hh));
                    }
                } else {         // k24,25: bias hi/lo (paired with B-x2 = 1.0)
                    float bb = e1_b[wr];
                    ushort hh = f2bf(bb);
                    A2[0] = (short)hh; A2[1] = (short)f2bf(bb - bf2f(hh));
                }
            } else if (sub == 3) {
                float bb = e2_b[wr];
                ushort hh = f2bf(bb);
                A2[0] = (short)hh; A2[1] = (short)f2bf(bb - bf2f(hh));
            }
        }
    };

    const int T0 = 2 * wv, T1 = 2 * wv + 1;
    bf16x8 A0h0, A0h1, A0l0, A0l1, A0x;
    bf16x8 A1h0, A1h1, A1l0, A1l1, A1x;
    bf16x8 A2h0, A2h1, A2l0, A2l1, A2x;
    loadA(T0, false, A0h0, A0h1, A0l0, A0l1, A0x);
    loadA(T1, false, A1h0, A1h1, A1l0, A1l1, A1x);
    if (wv == 7) loadA(0, true, A2h0, A2h1, A2l0, A2l1, A2x);

    __syncthreads();   // x_s ready

    // ---- init h parity0 = 0; x2 parity0 from x[0]; x2 constants both parities ----
    for (int i = t; i < 1024; i += 512) { ((ushort*)h_hi[0])[i] = 0; ((ushort*)h_lo[0])[i] = 0; }
    if (t < 384) {   // sb 0..2
        int sb = t >> 7, b = (t >> 3) & 15, j = t & 7;
        float xv = x_s[b * 772 + j];
        ushort hi = f2bf(xv);
        x2_s[0][sb][b][j] = (sb == 1) ? f2bf(xv - bf2f(hi)) : hi;
        x2_s[1][sb][b][j] = 0;
    } else if (t < 512) {   // sb 3: constants (1.0 at j=0,1) in both parities
        int b = (t >> 3) & 15, j = t & 7;
        ushort v = (j < 2) ? (ushort)0x3F80 : (ushort)0;
        x2_s[0][3][b][j] = v;
        x2_s[1][3][b][j] = v;
    }

    const int cb = l & 15;            // C/B-side batch
    const int u0_ = T0 * 4 + sub, u1_ = T1 * 4 + sub;   // units this lane owns
    float c0r = 0.f, c1r = 0.f;
    __syncthreads();

    #pragma unroll 1
    for (int ts = 0; ts < 96; ++ts) {
        const int p = ts & 1, pn = p ^ 1;

        // ---- B fragments: 5 dense b128 reads, shared by both tiles ----
        bf16x8 Bh0 = *(const bf16x8*)&h_hi[p][sub][cb][0];
        bf16x8 Bh1 = *(const bf16x8*)&h_hi[p][4 + sub][cb][0];
        bf16x8 Bl0 = *(const bf16x8*)&h_lo[p][sub][cb][0];
        bf16x8 Bl1 = *(const bf16x8*)&h_lo[p][4 + sub][cb][0];
        bf16x8 Bx  = *(const bf16x8*)&x2_s[p][sub][cb][0];

        f32x4 u0 = {0.f,0.f,0.f,0.f}, v0 = {0.f,0.f,0.f,0.f};
        u0 = __builtin_amdgcn_mfma_f32_16x16x32_bf16(A0h0, Bh0, u0, 0, 0, 0);
        u0 = __builtin_amdgcn_mfma_f32_16x16x32_bf16(A0l0, Bh0, u0, 0, 0, 0);
        u0 = __builtin_amdgcn_mfma_f32_16x16x32_bf16(A0h0, Bl0, u0, 0, 0, 0);
        v0 = __builtin_amdgcn_mfma_f32_16x16x32_bf16(A0h1, Bh1, v0, 0, 0, 0);
        v0 = __builtin_amdgcn_mfma_f32_16x16x32_bf16(A0l1, Bh1, v0, 0, 0, 0);
        v0 = __builtin_amdgcn_mfma_f32_16x16x32_bf16(A0h1, Bl1, v0, 0, 0, 0);
        v0 = __builtin_amdgcn_mfma_f32_16x16x32_bf16(A0x,  Bx,  v0, 0, 0, 0);

        f32x4 u1 = {0.f,0.f,0.f,0.f}, v1 = {0.f,0.f,0.f,0.f};
        u1 = __builtin_amdgcn_mfma_f32_16x16x32_bf16(A1h0, Bh0, u1, 0, 0, 0);
        u1 = __builtin_amdgcn_mfma_f32_16x16x32_bf16(A1l0, Bh0, u1, 0, 0, 0);
        u1 = __builtin_amdgcn_mfma_f32_16x16x32_bf16(A1h0, Bl0, u1, 0, 0, 0);
        v1 = __builtin_amdgcn_mfma_f32_16x16x32_bf16(A1h1, Bh1, v1, 0, 0, 0);
        v1 = __builtin_amdgcn_mfma_f32_16x16x32_bf16(A1l1, Bh1, v1, 0, 0, 0);
        v1 = __builtin_amdgcn_mfma_f32_16x16x32_bf16(A1h1, Bl1, v1, 0, 0, 0);
        v1 = __builtin_amdgcn_mfma_f32_16x16x32_bf16(A1x,  Bx,  v1, 0, 0, 0);

        if (wv == 7) {   // e2 xg tile: h entering this step -> pe2_s[ts-1]
            f32x4 u2 = {0.f,0.f,0.f,0.f}, v2 = {0.f,0.f,0.f,0.f};
            u2 = __builtin_amdgcn_mfma_f32_16x16x32_bf16(A2h0, Bh0, u2, 0, 0, 0);
            u2 = __builtin_amdgcn_mfma_f32_16x16x32_bf16(A2l0, Bh0, u2, 0, 0, 0);
            u2 = __builtin_amdgcn_mfma_f32_16x16x32_bf16(A2h0, Bl0, u2, 0, 0, 0);
            v2 = __builtin_amdgcn_mfma_f32_16x16x32_bf16(A2h1, Bh1, v2, 0, 0, 0);
            v2 = __builtin_amdgcn_mfma_f32_16x16x32_bf16(A2l1, Bh1, v2, 0, 0, 0);
            v2 = __builtin_amdgcn_mfma_f32_16x16x32_bf16(A2h1, Bl1, v2, 0, 0, 0);
            v2 = __builtin_amdgcn_mfma_f32_16x16x32_bf16(A2x,  Bx,  v2, 0, 0, 0);
            if (ts > 0 && sub == 0) {   // C rows 0-3 live in quad 0 (lanes 0-15)
                f32x4 acc2 = u2 + v2;
                #pragma unroll
                for (int i = 0; i < 4; ++i)
                    pe2_s[(ts - 1) * 64 + i * 16 + cb] = acc2[i];
            }
        }

        // ---- LSTM cells straight from accumulators (no transpose!) ----
        {
            f32x4 acc = u0 + v0;   // i,f,g,o of (batch cb, unit u0_)
            c0r = fmaf(sigm(acc[1]), c0r, sigm(acc[0]) * tanh_(acc[2]));
            float hv = sigm(acc[3]) * tanh_(c0r);
            ushort hh = f2bf(hv);
            h_hi[pn][u0_ >> 3][cb][u0_ & 7] = hh;
            h_lo[pn][u0_ >> 3][cb][u0_ & 7] = f2bf(hv - bf2f(hh));
        }
        {
            f32x4 acc = u1 + v1;
            c1r = fmaf(sigm(acc[1]), c1r, sigm(acc[0]) * tanh_(acc[2]));
            float hv = sigm(acc[3]) * tanh_(c1r);
            ushort hh = f2bf(hv);
            h_hi[pn][u1_ >> 3][cb][u1_ & 7] = hh;
            h_lo[pn][u1_ >> 3][cb][u1_ & 7] = f2bf(hv - bf2f(hh));
        }

        if (ts < 95 && t < 384) {   // build x2[pn] for ts+1
            int sb = t >> 7, b = (t >> 3) & 15, j = t & 7;
            float xv = x_s[b * 772 + (ts + 1) * 8 + j];
            ushort hi = f2bf(xv);
            x2_s[pn][sb][b][j] = (sb == 1) ? f2bf(xv - bf2f(hi)) : hi;
        }
        __syncthreads();
    }

    // ---- pe2[95] from final h (parity 0; A2x pairs only with constants) ----
    if (wv == 7) {
        bf16x8 Bh0 = *(const bf16x8*)&h_hi[0][sub][cb][0];
        bf16x8 Bh1 = *(const bf16x8*)&h_hi[0][4 + sub][cb][0];
        bf16x8 Bl0 = *(const bf16x8*)&h_lo[0][sub][cb][0];
        bf16x8 Bl1 = *(const bf16x8*)&h_lo[0][4 + sub][cb][0];
        bf16x8 Bx  = *(const bf16x8*)&x2_s[0][sub][cb][0];
        f32x4 u2 = {0.f,0.f,0.f,0.f}, v2 = {0.f,0.f,0.f,0.f};
        u2 = __builtin_amdgcn_mfma_f32_16x16x32_bf16(A2h0, Bh0, u2, 0, 0, 0);
        u2 = __builtin_amdgcn_mfma_f32_16x16x32_bf16(A2l0, Bh0, u2, 0, 0, 0);
        u2 = __builtin_amdgcn_mfma_f32_16x16x32_bf16(A2h0, Bl0, u2, 0, 0, 0);
        v2 = __builtin_amdgcn_mfma_f32_16x16x32_bf16(A2h1, Bh1, v2, 0, 0, 0);
        v2 = __builtin_amdgcn_mfma_f32_16x16x32_bf16(A2l1, Bh1, v2, 0, 0, 0);
        v2 = __builtin_amdgcn_mfma_f32_16x16x32_bf16(A2h1, Bl1, v2, 0, 0, 0);
        v2 = __builtin_amdgcn_mfma_f32_16x16x32_bf16(A2x,  Bx,  v2, 0, 0, 0);
        if (sub == 0) {
            f32x4 acc2 = u2 + v2;
            #pragma unroll
            for (int i = 0; i < 4; ++i)
                pe2_s[95 * 64 + i * 16 + cb] = acc2[i];
        }
    }
    __syncthreads();

    // ---- fused e2 recurrence: wave 0, lane = batch, 1-deep prefetch ----
    if (wv == 0 && l < 16) {
        const float w0 = e2_Whh[0], w1 = e2_Whh[1], w2 = e2_Whh[2], w3 = e2_Whh[3];
        float ni = pe2_s[l], nf = pe2_s[16 + l], ng = pe2_s[32 + l], no = pe2_s[48 + l];
        float h = 0.f, c = 0.f;
        #pragma unroll 1
        for (int ts = 0; ts < 96; ++ts) {
            float gi = ni, gf = nf, gg2 = ng, go = no;
            if (ts < 95) {
                int b2 = (ts + 1) * 64;
                ni = pe2_s[b2 + l]; nf = pe2_s[b2 + 16 + l];
                ng = pe2_s[b2 + 32 + l]; no = pe2_s[b2 + 48 + l];
            }
            gi = fmaf(h, w0, gi);
            gf = fmaf(h, w1, gf);
            gg2 = fmaf(h, w2, gg2);
            go = fmaf(h, w3, go);
            c = fmaf(sigm(gf), c, sigm(gi) * tanh_(gg2));
            h = sigm(go) * tanh_(c);
            dec_in[(size_t)ts * 4096 + bBase + l] = fmaxf(h, 0.f);
        }
    }
    // ---- x_aux rows (waves 1-8) ----
    if (wv >= 1 && wv <= 8) {
        int i = (wv - 1) * 64 + l;
        int B = i >> 5, j = i & 31;
        dec_in[(size_t)(96 + j) * 4096 + bBase + B] = x_s[B * 772 + (64 + j) * 8];
    }
}

// ============ K3: decoder fused (R6 known-good): d1(1->16) + d2(H=1) + fc1 + fc2 ============
__global__ __launch_bounds__(256, 2) void k3_dec(
    const float* __restrict__ dec_in,
    const float* __restrict__ d1_Wih, const float* __restrict__ d1_Whh, const float* __restrict__ d1_b,
    const float* __restrict__ d2_Wih, const float* __restrict__ d2_b,
    const float* __restrict__ d2_Whh,
    const float* __restrict__ fc1_W, const float* __restrict__ fc1_b,
    const float* __restrict__ fc2_W, const float* __restrict__ fc2_b,
    float* __restrict__ out)
{
    __shared__ float din_s[16 * 129];
    __shared__ float h_lds[16][16];
    __shared__ float pd2_s[16 * 516];
    __shared__ float d2h_s[16 * 132];
    __shared__ float mid_s[16 * 36];

    const int t = threadIdx.x;
    const int w = t >> 6, lane = t & 63;
    const int qq4 = lane >> 4, u = lane & 15;
    const int row = w * 4 + qq4;
    const size_t bBase = (size_t)blockIdx.x * 16;

    for (int i = t; i < 2048; i += 256) {
        int ts = i >> 4, rr = i & 15;
        din_s[rr * 129 + ts] = dec_in[(size_t)ts * 4096 + bBase + rr];
    }

    float wih_g[4], bg[4], whh_g[4][16], d2w[16];
    #pragma unroll
    for (int g = 0; g < 4; ++g) {
        wih_g[g] = d1_Wih[g * 16 + u];
        bg[g]    = d1_b[g * 16 + u];
        const float4* wp = (const float4*)(d1_Whh + (size_t)(g * 16 + u) * 16);
        #pragma unroll
        for (int k4 = 0; k4 < 4; ++k4) {
            float4 v = wp[k4];
            whh_g[g][4*k4+0] = v.x; whh_g[g][4*k4+1] = v.y;
            whh_g[g][4*k4+2] = v.z; whh_g[g][4*k4+3] = v.w;
        }
    }
    {
        const float4* wp = (const float4*)(d2_Wih + (size_t)(u & 3) * 16);
        #pragma unroll
        for (int k4 = 0; k4 < 4; ++k4) {
            float4 v = wp[k4];
            d2w[4*k4+0] = v.x; d2w[4*k4+1] = v.y; d2w[4*k4+2] = v.z; d2w[4*k4+3] = v.w;
        }
    }
    const float d2bias = d2_b[u & 3];

    float h = 0.f, c = 0.f;
    __syncthreads();

    float hv[16];
    for (int ts = 0; ts < 128; ++ts) {
        float xv = din_s[row * 129 + ts];
        float p0 = fmaf(xv, wih_g[0], bg[0]);
        float p1 = fmaf(xv, wih_g[1], bg[1]);
        float p2 = fmaf(xv, wih_g[2], bg[2]);
        float p3 = fmaf(xv, wih_g[3], bg[3]);
        if (ts > 0) {
            const float4* hp = (const float4*)&h_lds[row][0];
            #pragma unroll
            for (int k4 = 0; k4 < 4; ++k4) {
                float4 v = hp[k4];
                hv[4*k4+0] = v.x; hv[4*k4+1] = v.y; hv[4*k4+2] = v.z; hv[4*k4+3] = v.w;
            }
            #pragma unroll
            for (int k = 0; k < 16; ++k) {
                p0 = fmaf(hv[k], whh_g[0][k], p0);
                p1 = fmaf(hv[k], whh_g[1][k], p1);
                p2 = fmaf(hv[k], whh_g[2][k], p2);
                p3 = fmaf(hv[k], whh_g[3][k], p3);
            }
            if (u < 4) {
                float a = d2bias;
                #pragma unroll
                for (int k = 0; k < 16; ++k) a = fmaf(hv[k], d2w[k], a);
                pd2_s[row * 516 + (ts - 1) * 4 + u] = a;
            }
        }
        c = fmaf(sigm(p1), c, sigm(p0) * tanh_(p2));
        h = sigm(p3) * tanh_(c);
        h_lds[row][u] = h;
    }
    {
        const float4* hp = (const float4*)&h_lds[row][0];
        #pragma unroll
        for (int k4 = 0; k4 < 4; ++k4) {
            float4 v = hp[k4];
            hv[4*k4+0] = v.x; hv[4*k4+1] = v.y; hv[4*k4+2] = v.z; hv[4*k4+3] = v.w;
        }
        if (u < 4) {
            float a = d2bias;
            #pragma unroll
            for (int k = 0; k < 16; ++k) a = fmaf(hv[k], d2w[k], a);
            pd2_s[row * 516 + 127 * 4 + u] = a;
        }
    }
    __syncthreads();

    {
        const float w0 = d2_Whh[0], w1 = d2_Whh[1], w2 = d2_Whh[2], w3 = d2_Whh[3];
        if (t < 16) {
            float4 dbuf[4];
            #pragma unroll
            for (int j = 0; j < 4; ++j) dbuf[j] = *(const float4*)&pd2_s[t * 516 + j * 4];
            float h2 = 0.f, c2 = 0.f;
            #pragma unroll
            for (int ts = 0; ts < 128; ++ts) {
                float4 g4 = dbuf[ts & 3];
                if (ts + 4 < 128) dbuf[ts & 3] = *(const float4*)&pd2_s[t * 516 + (ts + 4) * 4];
                float gi = fmaf(h2, w0, g4.x);
                float gf = fmaf(h2, w1, g4.y);
                float gg = fmaf(h2, w2, g4.z);
                float go = fmaf(h2, w3, g4.w);
                c2 = fmaf(sigm(gf), c2, sigm(gi) * tanh_(gg));
                h2 = sigm(go) * tanh_(c2);
                d2h_s[t * 132 + ts] = h2;
            }
        }
    }
    __syncthreads();

    {
        const int bb = t >> 4, o = t & 15;
        float acc0 = fc1_b[o], acc1 = fc1_b[o + 16];
        const float4* wa = (const float4*)(fc1_W + (size_t)o * 128);
        const float4* wb = (const float4*)(fc1_W + (size_t)(o + 16) * 128);
        const float4* fp = (const float4*)&d2h_s[bb * 132];
        #pragma unroll
        for (int k4 = 0; k4 < 32; ++k4) {
            float4 f = fp[k4], va = wa[k4], vb = wb[k4];
            acc0 = fmaf(f.x, va.x, acc0); acc0 = fmaf(f.y, va.y, acc0);
            acc0 = fmaf(f.z, va.z, acc0); acc0 = fmaf(f.w, va.w, acc0);
            acc1 = fmaf(f.x, vb.x, acc1); acc1 = fmaf(f.y, vb.y, acc1);
            acc1 = fmaf(f.z, vb.z, acc1); acc1 = fmaf(f.w, vb.w, acc1);
        }
        mid_s[bb * 36 + o] = acc0;
        mid_s[bb * 36 + o + 16] = acc1;
        __syncthreads();
        float o0 = fc2_b[o], o1 = fc2_b[o + 16];
        const float4* va2 = (const float4*)(fc2_W + (size_t)o * 32);
        const float4* vb2 = (const float4*)(fc2_W + (size_t)(o + 16) * 32);
        const float4* mp = (const float4*)&mid_s[bb * 36];
        #pragma unroll
        for (int k4 = 0; k4 < 8; ++k4) {
            float4 m = mp[k4], va = va2[k4], vb = vb2[k4];
            o0 = fmaf(m.x, va.x, o0); o0 = fmaf(m.y, va.y, o0);
            o0 = fmaf(m.z, va.z, o0); o0 = fmaf(m.w, va.w, o0);
            o1 = fmaf(m.x, vb.x, o1); o1 = fmaf(m.y, vb.y, o1);
            o1 = fmaf(m.z, vb.z, o1); o1 = fmaf(m.w, vb.w, o1);
        }
        out[(bBase + bb) * 32 + o] = o0;
        out[(bBase + bb) * 32 + o + 16] = o1;
    }
}

extern "C" void kernel_launch(void* const* d_in, const int* in_sizes, int n_in,
                              void* d_out, int out_size, void* d_ws, size_t ws_size,
                              hipStream_t stream) {
    const float* x      = (const float*)d_in[0];
    const float* e1_Wih = (const float*)d_in[1];
    const float* e1_Whh = (const float*)d_in[2];
    const float* e1_b   = (const float*)d_in[3];
    const float* e2_Wih = (const float*)d_in[4];
    const float* e2_Whh = (const float*)d_in[5];
    const float* e2_b   = (const float*)d_in[6];
    const float* d1_Wih = (const float*)d_in[7];
    const float* d1_Whh = (const float*)d_in[8];
    const float* d1_b   = (const float*)d_in[9];
    const float* d2_Wih = (const float*)d_in[10];
    const float* d2_Whh = (const float*)d_in[11];
    const float* d2_b   = (const float*)d_in[12];
    const float* fc1_W  = (const float*)d_in[13];
    const float* fc1_b  = (const float*)d_in[14];
    const float* fc2_W  = (const float*)d_in[15];
    const float* fc2_b  = (const float*)d_in[16];
    float* out = (float*)d_out;

    float* dec_in = (float*)d_ws;       // [128][4096]

    hipLaunchKernelGGL(k1_enc, dim3(256), dim3(512), 0, stream,
                       x, e1_Wih, e1_Whh, e1_b, e2_Wih, e2_b, e2_Whh, dec_in);
    hipLaunchKernelGGL(k3_dec, dim3(256), dim3(256), 0, stream,
                       dec_in, d1_Wih, d1_Whh, d1_b, d2_Wih, d2_b, d2_Whh,
                       fc1_W, fc1_b, fc2_W, fc2_b, out);
}

// Round 11
// 157.265 us; speedup vs baseline: 1.4637x; 1.0071x over previous
//
#include <hip/hip_runtime.h>
#include <hip/hip_bf16.h>

typedef __attribute__((ext_vector_type(8))) short bf16x8;
typedef __attribute__((ext_vector_type(4))) float f32x4;

__device__ __forceinline__ float sigm(float x) {
    return __builtin_amdgcn_rcpf(1.0f + __expf(-x));
}
__device__ __forceinline__ float tanh_(float x) {
    float e = __expf(2.0f * x);
    return 1.0f - 2.0f * __builtin_amdgcn_rcpf(e + 1.0f);
}
__device__ __forceinline__ ushort f2bf(float f) {   // RNE float->bf16
    uint u = __float_as_uint(f);
    u = u + 0x7FFFu + ((u >> 16) & 1u);
    return (ushort)(u >> 16);
}
__device__ __forceinline__ float bf2f(ushort s) { return __uint_as_float(((uint)s) << 16); }

// ============ K1: e1 LSTM via MFMA, swapped operands, 16 waves x 1 tile ============
// 16 batches/block, 1024 threads (16 waves = 4/SIMD), grid 256.
// R9 evidence: 2 waves/SIMD cannot stream MFMAs (per-wave cadence ~20-30cy;
// MfmaUtil 17% x 2750cy/step = ~470 pipe-busy cy/SIMD for 14 MFMAs) nor hide
// LDS/cell latency. R8 evidence: 16 waves work IF per-wave VALU is small.
// This round: R8's wave structure + R9's cell-direct layout (~60 VALU/wave-step).
// Wave wv owns tile wv (units 4wv..4wv+3); wave 15 additionally owns the e2 tile.
// A = weights (VGPR-resident, loop-invariant), B = h from blocked LDS
// h[u>>3][batch][u&7]: 5 dense b128 reads/wave-step. Cells straight from C.
__global__ __launch_bounds__(1024) __attribute__((amdgpu_waves_per_eu(4, 4)))
void k1_enc(
    const float* __restrict__ x,
    const float* __restrict__ e1_Wih, const float* __restrict__ e1_Whh, const float* __restrict__ e1_b,
    const float* __restrict__ e2_Wih, const float* __restrict__ e2_b,
    const float* __restrict__ e2_Whh,
    float* __restrict__ dec_in)   // [ts][4096]
{
    __shared__ float x_s[16 * 772];                      // rows padded to 772
    __shared__ __align__(16) ushort h_hi[2][8][16][8];   // [parity][u-blk][batch][j]
    __shared__ __align__(16) ushort h_lo[2][8][16][8];
    __shared__ __align__(16) ushort x2_s[2][4][16][8];
    __shared__ __align__(16) float pe2_s[96 * 64];       // [ts][gate][batch]

    const int t = threadIdx.x;
    const int bBase = blockIdx.x * 16;
    const int wv = t >> 6, l = t & 63;
    const int row = l & 15, sub = l >> 4;    // A-side: gate-row, k-chunk; C-side: batch, unit-sub

    // ---- stage x ----
    for (int bb = 0; bb < 16; ++bb)
        for (int i = t; i < 768; i += 1024)
            x_s[bb * 772 + i] = x[(size_t)(bBase + bb) * 768 + i];

    // ---- A fragments (weights, hi/lo bf16) — loop-invariant ----
    auto loadW = [&](const float* rowbase, int k0, bool valid, bf16x8& hi8, bf16x8& lo8) {
        float f[8];
        if (valid) {
            float4 v0 = ((const float4*)(rowbase + k0))[0];
            float4 v1 = ((const float4*)(rowbase + k0))[1];
            f[0]=v0.x; f[1]=v0.y; f[2]=v0.z; f[3]=v0.w;
            f[4]=v1.x; f[5]=v1.y; f[6]=v1.z; f[7]=v1.w;
        } else {
            #pragma unroll
            for (int j = 0; j < 8; ++j) f[j] = 0.f;
        }
        #pragma unroll
        for (int j = 0; j < 8; ++j) {
            ushort h = f2bf(f[j]);
            hi8[j] = (short)h;
            lo8[j] = (short)f2bf(f[j] - bf2f(h));
        }
    };
    auto loadA = [&](int T, bool isE2, bf16x8& Ah0, bf16x8& Ah1, bf16x8& Al0, bf16x8& Al1, bf16x8& A2) {
        const int gate = row & 3, uq = row >> 2;
        const bool valid = !isE2 || (uq == 0);
        const int wr = isE2 ? gate : gate * 64 + T * 4 + uq;
        const float* rp = isE2 ? (e2_Wih + (size_t)wr * 64) : (e1_Whh + (size_t)wr * 64);
        loadW(rp, sub * 8,      valid, Ah0, Al0);
        loadW(rp, 32 + sub * 8, valid, Ah1, Al1);
        #pragma unroll
        for (int j = 0; j < 8; ++j) A2[j] = 0;
        if (valid) {
            if (!isE2) {
                if (sub < 3) {   // k0-7: Wih_hi(*xhi), 8-15: Wih_hi(*xlo), 16-23: Wih_lo(*xhi)
                    const float* wihr = e1_Wih + (size_t)wr * 8;
                    #pragma unroll
                    for (int j = 0; j < 8; ++j) {
                        float f = wihr[j];
                        ushort hh = f2bf(f);
                        A2[j] = (sub < 2) ? (short)hh : (short)f2bf(f - bf2f(hh));
                    }
                } else {         // k24,25: bias hi/lo (paired with B-x2 = 1.0)
                    float bb = e1_b[wr];
                    ushort hh = f2bf(bb);
                    A2[0] = (short)hh; A2[1] = (short)f2bf(bb - bf2f(hh));
                }
            } else if (sub == 3) {
                float bb = e2_b[wr];
                ushort hh = f2bf(bb);
                A2[0] = (short)hh; A2[1] = (short)f2bf(bb - bf2f(hh));
            }
        }
    };

    bf16x8 A0h0, A0h1, A0l0, A0l1, A0x;
    bf16x8 A2h0, A2h1, A2l0, A2l1, A2x;
    loadA(wv, false, A0h0, A0h1, A0l0, A0l1, A0x);
    if (wv == 15) loadA(0, true, A2h0, A2h1, A2l0, A2l1, A2x);

    __syncthreads();   // x_s ready

    // ---- init h parity0 = 0; x2 parity0 from x[0]; x2 constants both parities ----
    if (t < 1024) { ((ushort*)h_hi[0])[t] = 0; ((ushort*)h_lo[0])[t] = 0; }
    if (t < 384) {   // sb 0..2
        int sb = t >> 7, b = (t >> 3) & 15, j = t & 7;
        float xv = x_s[b * 772 + j];
        ushort hi = f2bf(xv);
        x2_s[0][sb][b][j] = (sb == 1) ? f2bf(xv - bf2f(hi)) : hi;
        x2_s[1][sb][b][j] = 0;
    } else if (t < 512) {   // sb 3: constants (1.0 at j=0,1) in both parities
        int b = (t >> 3) & 15, j = t & 7;
        ushort v = (j < 2) ? (ushort)0x3F80 : (ushort)0;
        x2_s[0][3][b][j] = v;
        x2_s[1][3][b][j] = v;
    }

    const int cb = l & 15;               // C/B-side batch
    const int u0_ = wv * 4 + sub;        // unit this lane owns
    float c0r = 0.f;
    __syncthreads();

    #pragma unroll 1
    for (int ts = 0; ts < 96; ++ts) {
        const int p = ts & 1, pn = p ^ 1;

        // ---- B fragments: 5 dense b128 reads ----
        bf16x8 Bh0 = *(const bf16x8*)&h_hi[p][sub][cb][0];
        bf16x8 Bh1 = *(const bf16x8*)&h_hi[p][4 + sub][cb][0];
        bf16x8 Bl0 = *(const bf16x8*)&h_lo[p][sub][cb][0];
        bf16x8 Bl1 = *(const bf16x8*)&h_lo[p][4 + sub][cb][0];
        bf16x8 Bx  = *(const bf16x8*)&x2_s[p][sub][cb][0];

        f32x4 u0 = {0.f,0.f,0.f,0.f}, v0 = {0.f,0.f,0.f,0.f};
        u0 = __builtin_amdgcn_mfma_f32_16x16x32_bf16(A0h0, Bh0, u0, 0, 0, 0);
        u0 = __builtin_amdgcn_mfma_f32_16x16x32_bf16(A0l0, Bh0, u0, 0, 0, 0);
        u0 = __builtin_amdgcn_mfma_f32_16x16x32_bf16(A0h0, Bl0, u0, 0, 0, 0);
        v0 = __builtin_amdgcn_mfma_f32_16x16x32_bf16(A0h1, Bh1, v0, 0, 0, 0);
        v0 = __builtin_amdgcn_mfma_f32_16x16x32_bf16(A0l1, Bh1, v0, 0, 0, 0);
        v0 = __builtin_amdgcn_mfma_f32_16x16x32_bf16(A0h1, Bl1, v0, 0, 0, 0);
        v0 = __builtin_amdgcn_mfma_f32_16x16x32_bf16(A0x,  Bx,  v0, 0, 0, 0);

        if (wv == 15) {   // e2 xg tile: h entering this step -> pe2_s[ts-1]
            f32x4 u2 = {0.f,0.f,0.f,0.f}, v2 = {0.f,0.f,0.f,0.f};
            u2 = __builtin_amdgcn_mfma_f32_16x16x32_bf16(A2h0, Bh0, u2, 0, 0, 0);
            u2 = __builtin_amdgcn_mfma_f32_16x16x32_bf16(A2l0, Bh0, u2, 0, 0, 0);
            u2 = __builtin_amdgcn_mfma_f32_16x16x32_bf16(A2h0, Bl0, u2, 0, 0, 0);
            v2 = __builtin_amdgcn_mfma_f32_16x16x32_bf16(A2h1, Bh1, v2, 0, 0, 0);
            v2 = __builtin_amdgcn_mfma_f32_16x16x32_bf16(A2l1, Bh1, v2, 0, 0, 0);
            v2 = __builtin_amdgcn_mfma_f32_16x16x32_bf16(A2h1, Bl1, v2, 0, 0, 0);
            v2 = __builtin_amdgcn_mfma_f32_16x16x32_bf16(A2x,  Bx,  v2, 0, 0, 0);
            if (ts > 0 && sub == 0) {   // C rows 0-3 live in lanes 0-15
                f32x4 acc2 = u2 + v2;
                #pragma unroll
                for (int i = 0; i < 4; ++i)
                    pe2_s[(ts - 1) * 64 + i * 16 + cb] = acc2[i];
            }
        }

        // ---- LSTM cell straight from accumulator ----
        {
            f32x4 acc = u0 + v0;   // i,f,g,o of (batch cb, unit u0_)
            c0r = fmaf(sigm(acc[1]), c0r, sigm(acc[0]) * tanh_(acc[2]));
            float hv = sigm(acc[3]) * tanh_(c0r);
            ushort hh = f2bf(hv);
            h_hi[pn][u0_ >> 3][cb][u0_ & 7] = hh;
            h_lo[pn][u0_ >> 3][cb][u0_ & 7] = f2bf(hv - bf2f(hh));
        }

        if (ts < 95 && t < 384) {   // build x2[pn] for ts+1
            int sb = t >> 7, b = (t >> 3) & 15, j = t & 7;
            float xv = x_s[b * 772 + (ts + 1) * 8 + j];
            ushort hi = f2bf(xv);
            x2_s[pn][sb][b][j] = (sb == 1) ? f2bf(xv - bf2f(hi)) : hi;
        }
        __syncthreads();
    }

    // ---- pe2[95] from final h (parity 0; A2x pairs only with bias constants) ----
    if (wv == 15) {
        bf16x8 Bh0 = *(const bf16x8*)&h_hi[0][sub][cb][0];
        bf16x8 Bh1 = *(const bf16x8*)&h_hi[0][4 + sub][cb][0];
        bf16x8 Bl0 = *(const bf16x8*)&h_lo[0][sub][cb][0];
        bf16x8 Bl1 = *(const bf16x8*)&h_lo[0][4 + sub][cb][0];
        bf16x8 Bx  = *(const bf16x8*)&x2_s[0][sub][cb][0];
        f32x4 u2 = {0.f,0.f,0.f,0.f}, v2 = {0.f,0.f,0.f,0.f};
        u2 = __builtin_amdgcn_mfma_f32_16x16x32_bf16(A2h0, Bh0, u2, 0, 0, 0);
        u2 = __builtin_amdgcn_mfma_f32_16x16x32_bf16(A2l0, Bh0, u2, 0, 0, 0);
        u2 = __builtin_amdgcn_mfma_f32_16x16x32_bf16(A2h0, Bl0, u2, 0, 0, 0);
        v2 = __builtin_amdgcn_mfma_f32_16x16x32_bf16(A2h1, Bh1, v2, 0, 0, 0);
        v2 = __builtin_amdgcn_mfma_f32_16x16x32_bf16(A2l1, Bh1, v2, 0, 0, 0);
        v2 = __builtin_amdgcn_mfma_f32_16x16x32_bf16(A2h1, Bl1, v2, 0, 0, 0);
        v2 = __builtin_amdgcn_mfma_f32_16x16x32_bf16(A2x,  Bx,  v2, 0, 0, 0);
        if (sub == 0) {
            f32x4 acc2 = u2 + v2;
            #pragma unroll
            for (int i = 0; i < 4; ++i)
                pe2_s[95 * 64 + i * 16 + cb] = acc2[i];
        }
    }
    __syncthreads();

    // ---- fused e2 recurrence: wave 0, lane = batch, 1-deep prefetch ----
    if (wv == 0 && l < 16) {
        const float w0 = e2_Whh[0], w1 = e2_Whh[1], w2 = e2_Whh[2], w3 = e2_Whh[3];
        float ni = pe2_s[l], nf = pe2_s[16 + l], ng = pe2_s[32 + l], no = pe2_s[48 + l];
        float h = 0.f, c = 0.f;
        #pragma unroll 1
        for (int ts = 0; ts < 96; ++ts) {
            float gi = ni, gf = nf, gg2 = ng, go = no;
            if (ts < 95) {
                int b2 = (ts + 1) * 64;
                ni = pe2_s[b2 + l]; nf = pe2_s[b2 + 16 + l];
                ng = pe2_s[b2 + 32 + l]; no = pe2_s[b2 + 48 + l];
            }
            gi = fmaf(h, w0, gi);
            gf = fmaf(h, w1, gf);
            gg2 = fmaf(h, w2, gg2);
            go = fmaf(h, w3, go);
            c = fmaf(sigm(gf), c, sigm(gi) * tanh_(gg2));
            h = sigm(go) * tanh_(c);
            dec_in[(size_t)ts * 4096 + bBase + l] = fmaxf(h, 0.f);
        }
    }
    // ---- x_aux rows (waves 1-8) ----
    if (wv >= 1 && wv <= 8) {
        int i = (wv - 1) * 64 + l;
        int B = i >> 5, j = i & 31;
        dec_in[(size_t)(96 + j) * 4096 + bBase + B] = x_s[B * 772 + (64 + j) * 8];
    }
}

// ============ K3: decoder fused (R6 known-good): d1(1->16) + d2(H=1) + fc1 + fc2 ============
__global__ __launch_bounds__(256, 2) void k3_dec(
    const float* __restrict__ dec_in,
    const float* __restrict__ d1_Wih, const float* __restrict__ d1_Whh, const float* __restrict__ d1_b,
    const float* __restrict__ d2_Wih, const float* __restrict__ d2_b,
    const float* __restrict__ d2_Whh,
    const float* __restrict__ fc1_W, const float* __restrict__ fc1_b,
    const float* __restrict__ fc2_W, const float* __restrict__ fc2_b,
    float* __restrict__ out)
{
    __shared__ float din_s[16 * 129];
    __shared__ float h_lds[16][16];
    __shared__ float pd2_s[16 * 516];
    __shared__ float d2h_s[16 * 132];
    __shared__ float mid_s[16 * 36];

    const int t = threadIdx.x;
    const int w = t >> 6, lane = t & 63;
    const int qq4 = lane >> 4, u = lane & 15;
    const int row = w * 4 + qq4;
    const size_t bBase = (size_t)blockIdx.x * 16;

    for (int i = t; i < 2048; i += 256) {
        int ts = i >> 4, rr = i & 15;
        din_s[rr * 129 + ts] = dec_in[(size_t)ts * 4096 + bBase + rr];
    }

    float wih_g[4], bg[4], whh_g[4][16], d2w[16];
    #pragma unroll
    for (int g = 0; g < 4; ++g) {
        wih_g[g] = d1_Wih[g * 16 + u];
        bg[g]    = d1_b[g * 16 + u];
        const float4* wp = (const float4*)(d1_Whh + (size_t)(g * 16 + u) * 16);
        #pragma unroll
        for (int k4 = 0; k4 < 4; ++k4) {
            float4 v = wp[k4];
            whh_g[g][4*k4+0] = v.x; whh_g[g][4*k4+1] = v.y;
            whh_g[g][4*k4+2] = v.z; whh_g[g][4*k4+3] = v.w;
        }
    }
    {
        const float4* wp = (const float4*)(d2_Wih + (size_t)(u & 3) * 16);
        #pragma unroll
        for (int k4 = 0; k4 < 4; ++k4) {
            float4 v = wp[k4];
            d2w[4*k4+0] = v.x; d2w[4*k4+1] = v.y; d2w[4*k4+2] = v.z; d2w[4*k4+3] = v.w;
        }
    }
    const float d2bias = d2_b[u & 3];

    float h = 0.f, c = 0.f;
    __syncthreads();

    float hv[16];
    for (int ts = 0; ts < 128; ++ts) {
        float xv = din_s[row * 129 + ts];
        float p0 = fmaf(xv, wih_g[0], bg[0]);
        float p1 = fmaf(xv, wih_g[1], bg[1]);
        float p2 = fmaf(xv, wih_g[2], bg[2]);
        float p3 = fmaf(xv, wih_g[3], bg[3]);
        if (ts > 0) {
            const float4* hp = (const float4*)&h_lds[row][0];
            #pragma unroll
            for (int k4 = 0; k4 < 4; ++k4) {
                float4 v = hp[k4];
                hv[4*k4+0] = v.x; hv[4*k4+1] = v.y; hv[4*k4+2] = v.z; hv[4*k4+3] = v.w;
            }
            #pragma unroll
            for (int k = 0; k < 16; ++k) {
                p0 = fmaf(hv[k], whh_g[0][k], p0);
                p1 = fmaf(hv[k], whh_g[1][k], p1);
                p2 = fmaf(hv[k], whh_g[2][k], p2);
                p3 = fmaf(hv[k], whh_g[3][k], p3);
            }
            if (u < 4) {
                float a = d2bias;
                #pragma unroll
                for (int k = 0; k < 16; ++k) a = fmaf(hv[k], d2w[k], a);
                pd2_s[row * 516 + (ts - 1) * 4 + u] = a;
            }
        }
        c = fmaf(sigm(p1), c, sigm(p0) * tanh_(p2));
        h = sigm(p3) * tanh_(c);
        h_lds[row][u] = h;
    }
    {
        const float4* hp = (const float4*)&h_lds[row][0];
        #pragma unroll
        for (int k4 = 0; k4 < 4; ++k4) {
            float4 v = hp[k4];
            hv[4*k4+0] = v.x; hv[4*k4+1] = v.y; hv[4*k4+2] = v.z; hv[4*k4+3] = v.w;
        }
        if (u < 4) {
            float a = d2bias;
            #pragma unroll
            for (int k = 0; k < 16; ++k) a = fmaf(hv[k], d2w[k], a);
            pd2_s[row * 516 + 127 * 4 + u] = a;
        }
    }
    __syncthreads();

    {
        const float w0 = d2_Whh[0], w1 = d2_Whh[1], w2 = d2_Whh[2], w3 = d2_Whh[3];
        if (t < 16) {
            float4 dbuf[4];
            #pragma unroll
            for (int j = 0; j < 4; ++j) dbuf[j] = *(const float4*)&pd2_s[t * 516 + j * 4];
            float h2 = 0.f, c2 = 0.f;
            #pragma unroll
            for (int ts = 0; ts < 128; ++ts) {
                float4 g4 = dbuf[ts & 3];
                if (ts + 4 < 128) dbuf[ts & 3] = *(const float4*)&pd2_s[t * 516 + (ts + 4) * 4];
                float gi = fmaf(h2, w0, g4.x);
                float gf = fmaf(h2, w1, g4.y);
                float gg = fmaf(h2, w2, g4.z);
                float go = fmaf(h2, w3, g4.w);
                c2 = fmaf(sigm(gf), c2, sigm(gi) * tanh_(gg));
                h2 = sigm(go) * tanh_(c2);
                d2h_s[t * 132 + ts] = h2;
            }
        }
    }
    __syncthreads();

    {
        const int bb = t >> 4, o = t & 15;
        float acc0 = fc1_b[o], acc1 = fc1_b[o + 16];
        const float4* wa = (const float4*)(fc1_W + (size_t)o * 128);
        const float4* wb = (const float4*)(fc1_W + (size_t)(o + 16) * 128);
        const float4* fp = (const float4*)&d2h_s[bb * 132];
        #pragma unroll
        for (int k4 = 0; k4 < 32; ++k4) {
            float4 f = fp[k4], va = wa[k4], vb = wb[k4];
            acc0 = fmaf(f.x, va.x, acc0); acc0 = fmaf(f.y, va.y, acc0);
            acc0 = fmaf(f.z, va.z, acc0); acc0 = fmaf(f.w, va.w, acc0);
            acc1 = fmaf(f.x, vb.x, acc1); acc1 = fmaf(f.y, vb.y, acc1);
            acc1 = fmaf(f.z, vb.z, acc1); acc1 = fmaf(f.w, vb.w, acc1);
        }
        mid_s[bb * 36 + o] = acc0;
        mid_s[bb * 36 + o + 16] = acc1;
        __syncthreads();
        float o0 = fc2_b[o], o1 = fc2_b[o + 16];
        const float4* va2 = (const float4*)(fc2_W + (size_t)o * 32);
        const float4* vb2 = (const float4*)(fc2_W + (size_t)(o + 16) * 32);
        const float4* mp = (const float4*)&mid_s[bb * 36];
        #pragma unroll
        for (int k4 = 0; k4 < 8; ++k4) {
            float4 m = mp[k4], va = va2[k4], vb = vb2[k4];
            o0 = fmaf(m.x, va.x, o0); o0 = fmaf(m.y, va.y, o0);
            o0 = fmaf(m.z, va.z, o0); o0 = fmaf(m.w, va.w, o0);
            o1 = fmaf(m.x, vb.x, o1); o1 = fmaf(m.y, vb.y, o1);
            o1 = fmaf(m.z, vb.z, o1); o1 = fmaf(m.w, vb.w, o1);
        }
        out[(bBase + bb) * 32 + o] = o0;
        out[(bBase + bb) * 32 + o + 16] = o1;
    }
}

extern "C" void kernel_launch(void* const* d_in, const int* in_sizes, int n_in,
                              void* d_out, int out_size, void* d_ws, size_t ws_size,
                              hipStream_t stream) {
    const float* x      = (const float*)d_in[0];
    const float* e1_Wih = (const float*)d_in[1];
    const float* e1_Whh = (const float*)d_in[2];
    const float* e1_b   = (const float*)d_in[3];
    const float* e2_Wih = (const float*)d_in[4];
    const float* e2_Whh = (const float*)d_in[5];
    const float* e2_b   = (const float*)d_in[6];
    const float* d1_Wih = (const float*)d_in[7];
    const float* d1_Whh = (const float*)d_in[8];
    const float* d1_b   = (const float*)d_in[9];
    const float* d2_Wih = (const float*)d_in[10];
    const float* d2_Whh = (const float*)d_in[11];
    const float* d2_b   = (const float*)d_in[12];
    const float* fc1_W  = (const float*)d_in[13];
    const float* fc1_b  = (const float*)d_in[14];
    const float* fc2_W  = (const float*)d_in[15];
    const float* fc2_b  = (const float*)d_in[16];
    float* out = (float*)d_out;

    float* dec_in = (float*)d_ws;       // [128][4096]

    hipLaunchKernelGGL(k1_enc, dim3(256), dim3(1024), 0, stream,
                       x, e1_Wih, e1_Whh, e1_b, e2_Wih, e2_b, e2_Whh, dec_in);
    hipLaunchKernelGGL(k3_dec, dim3(256), dim3(256), 0, stream,
                       dec_in, d1_Wih, d1_Whh, d1_b, d2_Wih, d2_b, d2_Whh,
                       fc1_W, fc1_b, fc2_W, fc2_b, out);
}